// Round 9
// baseline (182.378 us; speedup 1.0000x reference)
//
#include <hip/hip_runtime.h>
#include <stdint.h>

// Pipeline: cvt x,z -> bf16; pack weights; fused QKV GEMM (256x128 tile, 128x64/wave,
// 3-slot ring counted-vmcnt); flash attention (causal, paired q-blocks, 2-phase dbuf);
// output GEMM -> f32.
// B=8 TX=TZ=1024 DX=DZ=1024 DATT=DMID=64 H=16 DOUT=1024.

typedef float    f32x4  __attribute__((ext_vector_type(4)));
typedef __bf16   bf16x8 __attribute__((ext_vector_type(8)));
typedef unsigned short u16x4 __attribute__((ext_vector_type(4)));
typedef unsigned short u16x8 __attribute__((ext_vector_type(8)));

#define MASKNEG (-3.0e38f)
#define QSCALE_F (0.125f * 1.4426950408889634f)

__device__ __forceinline__ unsigned short f2bf(float f) {
  unsigned int u = __float_as_uint(f);
  u += 0x7fffu + ((u >> 16) & 1u);   // RNE
  return (unsigned short)(u >> 16);
}

__device__ __forceinline__ void gload16(const void* g, void* s) {
  const __attribute__((address_space(1))) unsigned int* gp =
      (const __attribute__((address_space(1))) unsigned int*)(uintptr_t)g;
  __attribute__((address_space(3))) unsigned int* lp =
      (__attribute__((address_space(3))) unsigned int*)(unsigned int)(uintptr_t)s;
  __builtin_amdgcn_global_load_lds(gp, lp, 16, 0, 0);
}

__device__ __forceinline__ f32x4 mfma16(bf16x8 a, bf16x8 b, f32x4 c) {
  return __builtin_amdgcn_mfma_f32_16x16x32_bf16(a, b, c, 0, 0, 0);
}

// ---------------- prep kernels ----------------

__global__ __launch_bounds__(256) void k_cvt2(const float* __restrict__ x,
                                              const float* __restrict__ z,
                                              unsigned short* __restrict__ out) {
  int i = blockIdx.x * 256 + threadIdx.x;
  const int stride = gridDim.x * 256;
  for (; i < 2097152; i += stride) {
    const float* in = (i < 1048576) ? (x + (size_t)i * 8) : (z + (size_t)(i - 1048576) * 8);
    const f32x4* p = (const f32x4*)in;
    f32x4 a = p[0], b = p[1];
    u16x8 o;
    o[0] = f2bf(a[0]); o[1] = f2bf(a[1]); o[2] = f2bf(a[2]); o[3] = f2bf(a[3]);
    o[4] = f2bf(b[0]); o[5] = f2bf(b[1]); o[6] = f2bf(b[2]); o[7] = f2bf(b[3]);
    *(u16x8*)(out + (size_t)i * 8) = o;
  }
}

// All weight packs in one launch, grid (16,16,4).
__global__ __launch_bounds__(256) void k_pack(const float* __restrict__ Wq,
                                              const float* __restrict__ Wk,
                                              const float* __restrict__ Wv,
                                              const float* __restrict__ Wp,
                                              unsigned short* __restrict__ Oq,
                                              unsigned short* __restrict__ Ok,
                                              unsigned short* __restrict__ Ov,
                                              unsigned short* __restrict__ Op) {
  __shared__ float tile[64][65];
  const int t = threadIdx.x;
  const int zid = blockIdx.z;
  if (zid < 3) {
    const float* W = zid == 0 ? Wq : (zid == 1 ? Wk : Wv);
    unsigned short* O = zid == 0 ? Oq : (zid == 1 ? Ok : Ov);
    const int h = blockIdx.x, d0 = blockIdx.y * 64;
    const int ee = t & 63, r0 = t >> 6;
#pragma unroll
    for (int dd = r0; dd < 64; dd += 4)
      tile[dd][ee] = W[(h * 1024 + d0 + dd) * 64 + ee];
    __syncthreads();
    const int d = t & 63, e0 = t >> 6;
#pragma unroll
    for (int e = e0; e < 64; e += 4)
      O[(h * 64 + e) * 1024 + d0 + d] = f2bf(tile[d][e]);
  } else {
    const int k0 = blockIdx.x * 64, n0 = blockIdx.y * 64;
    const int nn = t & 63, r0 = t >> 6;
#pragma unroll
    for (int kk = r0; kk < 64; kk += 4)
      tile[kk][nn] = Wp[(k0 + kk) * 1024 + n0 + nn];
    __syncthreads();
    const int kk = t & 63, e0 = t >> 6;
#pragma unroll
    for (int n2 = e0; n2 < 64; n2 += 4)
      Op[(n0 + n2) * 1024 + k0 + kk] = f2bf(tile[kk][n2]);
  }
}

// ---------------- GEMM body: C[256x128 tile] = A * Bt^T + bias ----------------
// 4 waves, per-wave 128x64 output (acc[8][4]) -> 562 B LDS traffic per MFMA (vs 750
// at 64x64/wave): LDS-BW cap ~54% MfmaUtil. 3-slot ring, counted vmcnt(6).
// As: 3 x 16 KB (256 rows x 64 B). Bs: 3 x 8 KB (128 rows x 64 B). 72 KB LDS.
// mode 0: bf16 out to [bh][x][64] (Q/K), scaled by oscale
// mode 2: bf16 out to [bh][e][z]  (V transposed)
// mode 3: f32 out, row-major (final projection)
__device__ __forceinline__ void gemm_body(const unsigned short* __restrict__ A,
                                          const unsigned short* __restrict__ Bt,
                                          const float* __restrict__ bias,
                                          void* __restrict__ outp,
                                          int mode, float oscale,
                                          int brow, int bcol,
                                          unsigned short* As, unsigned short* Bs) {
  const int tid = threadIdx.x;
  const int l = tid & 63, w = tid >> 6;
  const int lrow = l & 15, lk = l >> 4;
  const int wr = (w >> 1) * 128, wc = (w & 1) * 64;

  const int arow = tid >> 2;  // 0..63
  const int asrc = ((tid & 3) ^ ((arow >> 1) & 3)) * 8;  // invariant under arow+=64
  const unsigned short* ag0 = A + (size_t)(brow + arow) * 1024 + asrc;
  const unsigned short* bg0 = Bt + (size_t)(bcol + arow) * 1024 + asrc;

  int aoff[8], boff[4];
#pragma unroll
  for (int m = 0; m < 8; m++) {
    int row = wr + m * 16 + lrow;
    aoff[m] = row * 64 + ((lk ^ ((row >> 1) & 3)) << 4);
  }
#pragma unroll
  for (int n = 0; n < 4; n++) {
    int col = wc + n * 16 + lrow;
    boff[n] = col * 64 + ((lk ^ ((col >> 1) & 3)) << 4);
  }

  f32x4 acc[8][4];
#pragma unroll
  for (int n = 0; n < 4; n++) {
    float bv = bias[bcol + wc + n * 16 + lrow];
#pragma unroll
    for (int m = 0; m < 8; m++) acc[m][n] = (f32x4){bv, bv, bv, bv};
  }

  // stage tile kt into ring slot: A 4 x 4KB rounds (rows +64), B 2 rounds. 6 loads.
#define STAGE_G(kt, slot)                                                  \
  {                                                                        \
    char* asb = (char*)As + (slot) * 32768 + w * 1024;                     \
    char* bsb = (char*)Bs + (slot) * 16384 + w * 1024;                     \
    gload16(ag0 + (kt) * 32,          asb);                                \
    gload16(ag0 + (kt) * 32 + 65536,  asb + 4096);                         \
    gload16(ag0 + (kt) * 32 + 131072, asb + 8192);                         \
    gload16(ag0 + (kt) * 32 + 196608, asb + 12288);                        \
    gload16(bg0 + (kt) * 32,          bsb);                                \
    gload16(bg0 + (kt) * 32 + 65536,  bsb + 4096);                         \
  }

  // prologue: tiles 0,1 staged (12 loads); wait tile 0 (6 newest still in flight)
  STAGE_G(0, 0)
  STAGE_G(1, 1)
  asm volatile("s_waitcnt vmcnt(6)" ::: "memory");
  __builtin_amdgcn_s_barrier();
  __builtin_amdgcn_sched_barrier(0);

  int s0 = 0, s2 = 2;
#pragma unroll 1
  for (int kt = 0; kt < 32; kt++) {
    if (kt < 30) STAGE_G(kt + 2, s2)
    const char* ab = (const char*)As + s0 * 32768;
    const char* bb = (const char*)Bs + s0 * 16384;
    bf16x8 bfr[4];
#pragma unroll
    for (int n = 0; n < 4; n++) bfr[n] = *(const bf16x8*)(bb + boff[n]);
#pragma unroll
    for (int m = 0; m < 8; m++) {
      bf16x8 af = *(const bf16x8*)(ab + aoff[m]);
#pragma unroll
      for (int n = 0; n < 4; n++)
        acc[m][n] = mfma16(af, bfr[n], acc[m][n]);
    }
    if (kt < 31) {  // tile kt+1 ready; kt+2's 6 loads stay in flight across barrier
      if (kt < 30) {
        asm volatile("s_waitcnt vmcnt(6)" ::: "memory");
      } else {
        asm volatile("s_waitcnt vmcnt(0)" ::: "memory");
      }
      __builtin_amdgcn_s_barrier();
      __builtin_amdgcn_sched_barrier(0);
    }
    s0 = (s0 == 2) ? 0 : s0 + 1;
    s2 = (s2 == 2) ? 0 : s2 + 1;
  }
#undef STAGE_G

  if (mode == 0) {
    unsigned short* C = (unsigned short*)outp;
#pragma unroll
    for (int m = 0; m < 8; m++) {
      int r = brow + wr + m * 16 + 4 * lk;
#pragma unroll
      for (int n = 0; n < 4; n++) {
        int c = bcol + wc + n * 16 + lrow;
        unsigned short* p = C + ((r >> 10) * 16 + (c >> 6)) * 65536 + (r & 1023) * 64 + (c & 63);
#pragma unroll
        for (int j = 0; j < 4; j++) p[j * 64] = f2bf(acc[m][n][j] * oscale);
      }
    }
  } else if (mode == 2) {
    unsigned short* C = (unsigned short*)outp;
#pragma unroll
    for (int m = 0; m < 8; m++) {
      int r = brow + wr + m * 16 + 4 * lk;
#pragma unroll
      for (int n = 0; n < 4; n++) {
        int c = bcol + wc + n * 16 + lrow;
        u16x4 o;
#pragma unroll
        for (int j = 0; j < 4; j++) o[j] = f2bf(acc[m][n][j]);
        *(u16x4*)(C + ((r >> 10) * 16 + (c >> 6)) * 65536 + (c & 63) * 1024 + (r & 1023)) = o;
      }
    }
  } else {
    float* C = (float*)outp;
#pragma unroll
    for (int m = 0; m < 8; m++) {
      int r = brow + wr + m * 16 + 4 * lk;
#pragma unroll
      for (int n = 0; n < 4; n++) {
        int c = bcol + wc + n * 16 + lrow;
#pragma unroll
        for (int j = 0; j < 4; j++) C[(r + j) * 1024 + c] = acc[m][n][j];
      }
    }
  }
}

// fused QKV: grid (32, 24); y>>3 = segment (0=Q,1=K,2=V), y&7 = col tile (128 wide)
__global__ __launch_bounds__(256, 2) void k_gemm_qkv(const unsigned short* __restrict__ Xb,
                                                     const unsigned short* __restrict__ Zb,
                                                     const unsigned short* __restrict__ Wqkv,
                                                     const float* __restrict__ bq,
                                                     const float* __restrict__ bk,
                                                     const float* __restrict__ bv,
                                                     unsigned short* __restrict__ Qp,
                                                     unsigned short* __restrict__ Kp,
                                                     unsigned short* __restrict__ Vtp) {
  __shared__ unsigned short As[49152];  // 3 x 16 KB
  __shared__ unsigned short Bs[24576];  // 3 x 8 KB  -> 72 KB total (as shorts/2)
  const int brow = blockIdx.x * 256;
  const int cg = blockIdx.y;
  const int seg = cg >> 3;
  const int bcol = (cg & 7) * 128;
  const unsigned short* A = (seg == 0) ? Xb : Zb;
  const unsigned short* Bt = Wqkv + (size_t)seg * 1048576;
  const float* bias = (seg == 0) ? bq : (seg == 1 ? bk : bv);
  void* outp = (seg == 0) ? (void*)Qp : (seg == 1 ? (void*)Kp : (void*)Vtp);
  const int mode = (seg == 2) ? 2 : 0;
  const float oscale = (seg == 0) ? QSCALE_F : 1.0f;
  gemm_body(A, Bt, bias, outp, mode, oscale, brow, bcol, As, Bs);
}

// final projection: grid (32, 8), f32 out
__global__ __launch_bounds__(256, 2) void k_gemm(const unsigned short* __restrict__ A,
                                                 const unsigned short* __restrict__ Bt,
                                                 const float* __restrict__ bias,
                                                 void* __restrict__ outp,
                                                 int mode, float oscale) {
  __shared__ unsigned short As[49152];
  __shared__ unsigned short Bs[24576];
  gemm_body(A, Bt, bias, outp, mode, oscale, blockIdx.x * 256, blockIdx.y * 128, As, Bs);
}

// ---------------- flash attention (round-1 orientation, paired q-blocks, 2-phase) ----------------
// (byte-identical to round-7/8 passing version)
__global__ __launch_bounds__(256) void k_attn(const unsigned short* __restrict__ Qh,
                                              const unsigned short* __restrict__ Kh,
                                              const unsigned short* __restrict__ Vth,
                                              unsigned short* __restrict__ Y) {
  __shared__ unsigned short Ks[8192];
  __shared__ unsigned short Vs[8192];
  __shared__ unsigned short Ps[8192];

  const int tid = threadIdx.x, l = tid & 63, w = tid >> 6;
  const int lrow = l & 15, lk = l >> 4;
  const int bh = blockIdx.y;
  const int pp = blockIdx.x;

  const unsigned short* Qb = Qh + bh * 65536;
  const unsigned short* Kb = Kh + bh * 65536;
  const unsigned short* Vb = Vth + bh * 65536;

  bf16x8 ones;
#pragma unroll
  for (int j = 0; j < 8; j++) ones[j] = (__bf16)1.0f;

  const int srow = tid >> 3;
  const int swz = ((tid & 7) ^ (srow & 7)) * 8;
  const unsigned short* kg0 = Kb + srow * 64 + swz;
  const unsigned short* kg1 = Kb + (srow + 32) * 64 + swz;
  const unsigned short* vg0 = Vb + srow * 1024 + swz;
  const unsigned short* vg1 = Vb + (srow + 32) * 1024 + swz;
  char* pw = (char*)Ps + w * 4096;

  const int b = bh >> 4, h = bh & 15;

#pragma unroll 1
  for (int half = 0; half < 2; half++) {
    const int qi = half == 0 ? (7 - pp) : pp;
    const int qw = qi * 128 + w * 32;
    const int qmax = qw + 31;

    bf16x8 qf[2][2];
#pragma unroll
    for (int qn = 0; qn < 2; qn++) {
      const unsigned short* qp = Qb + (qw + qn * 16 + lrow) * 64 + lk * 8;
      qf[qn][0] = *(const bf16x8*)qp;
      qf[qn][1] = *(const bf16x8*)(qp + 32);
    }

    f32x4 m[2], lsum[2], yacc[2][4];
#pragma unroll
    for (int qn = 0; qn < 2; qn++) {
      m[qn] = (f32x4){MASKNEG, MASKNEG, MASKNEG, MASKNEG};
      lsum[qn] = (f32x4){0.f, 0.f, 0.f, 0.f};
#pragma unroll
      for (int ef = 0; ef < 4; ef++) yacc[qn][ef] = (f32x4){0.f, 0.f, 0.f, 0.f};
    }

    const int nt = qi * 2 + 2;

    {
      char* ksb = (char*)Ks + w * 1024;
      char* vsb = (char*)Vs + w * 1024;
      gload16(kg0, ksb);
      gload16(kg1, ksb + 4096);
      gload16(vg0, vsb);
      gload16(vg1, vsb + 4096);
    }
    __syncthreads();

#pragma unroll 1
    for (int t = 0; t < nt; t++) {
      const int z0 = t * 64;
      const int cur = t & 1;
      if (t < nt - 1) {
        const int zn = (t + 1) * 64;
        char* ksb = (char*)Ks + (cur ^ 1) * 8192 + w * 1024;
        char* vsb = (char*)Vs + (cur ^ 1) * 8192 + w * 1024;
        gload16(kg0 + zn * 64, ksb);
        gload16(kg1 + zn * 64, ksb + 4096);
        gload16(vg0 + zn, vsb);
        gload16(vg1 + zn, vsb + 4096);
      }

      if (z0 <= qmax) {
        const char* kbase = (const char*)Ks + cur * 8192;
        const char* vbase = (const char*)Vs + cur * 8192;

        f32x4 s[2][4];
#pragma unroll
        for (int qn = 0; qn < 2; qn++)
#pragma unroll
          for (int zf = 0; zf < 4; zf++) s[qn][zf] = (f32x4){0.f, 0.f, 0.f, 0.f};
#pragma unroll
        for (int zf = 0; zf < 4; zf++) {
          int zr = zf * 16 + lrow;
#pragma unroll
          for (int kf = 0; kf < 2; kf++) {
            bf16x8 kfr = *(const bf16x8*)(kbase + zr * 128 + (((kf * 4 + lk) ^ (zr & 7)) << 4));
            s[0][zf] = mfma16(qf[0][kf], kfr, s[0][zf]);
            s[1][zf] = mfma16(qf[1][kf], kfr, s[1][zf]);
          }
        }

        if (z0 + 63 > qw) {
#pragma unroll
          for (int qn = 0; qn < 2; qn++) {
            int qbase = qw + qn * 16 + 4 * lk;
#pragma unroll
            for (int zf = 0; zf < 4; zf++) {
              int zg = z0 + zf * 16 + lrow;
#pragma unroll
              for (int j = 0; j < 4; j++)
                if (zg > qbase + j) s[qn][zf][j] = MASKNEG;
            }
          }
        }

#pragma unroll
        for (int qn = 0; qn < 2; qn++) {
#pragma unroll
          for (int j = 0; j < 4; j++) {
            float rm = fmaxf(fmaxf(s[qn][0][j], s[qn][1][j]), fmaxf(s[qn][2][j], s[qn][3][j]));
            rm = fmaxf(rm, __shfl_xor(rm, 1));
            rm = fmaxf(rm, __shfl_xor(rm, 2));
            rm = fmaxf(rm, __shfl_xor(rm, 4));
            rm = fmaxf(rm, __shfl_xor(rm, 8));
            float mn = fmaxf(m[qn][j], rm);
            float a = __builtin_amdgcn_exp2f(m[qn][j] - mn);
            m[qn][j] = mn;
            lsum[qn][j] *= a;
#pragma unroll
            for (int ef = 0; ef < 4; ef++) yacc[qn][ef][j] *= a;
#pragma unroll
            for (int zf = 0; zf < 4; zf++)
              s[qn][zf][j] = __builtin_amdgcn_exp2f(s[qn][zf][j] - mn);
          }

#pragma unroll
          for (int zf = 0; zf < 4; zf++) {
            int zc = zf * 16 + lrow;
            int zp = zc >> 3;
#pragma unroll
            for (int j = 0; j < 4; j++) {
              int q = 4 * lk + j;
              *(unsigned short*)(pw + (qn * 16 + q) * 128 + ((zp ^ (q & 7)) << 4) + (zc & 7) * 2)
                  = f2bf(s[qn][zf][j]);
            }
          }
        }

        asm volatile("s_waitcnt lgkmcnt(0)" ::: "memory");
        __builtin_amdgcn_sched_barrier(0);

        bf16x8 pf[2][2];
#pragma unroll
        for (int qn = 0; qn < 2; qn++)
#pragma unroll
          for (int kf = 0; kf < 2; kf++)
            pf[qn][kf] = *(const bf16x8*)(pw + (qn * 16 + lrow) * 128 + (((kf * 4 + lk) ^ (lrow & 7)) << 4));

#pragma unroll
        for (int qn = 0; qn < 2; qn++)
#pragma unroll
          for (int kf = 0; kf < 2; kf++)
            lsum[qn] = mfma16(pf[qn][kf], ones, lsum[qn]);

#pragma unroll
        for (int ef = 0; ef < 4; ef++) {
          int er = ef * 16 + lrow;
#pragma unroll
          for (int kf = 0; kf < 2; kf++) {
            bf16x8 vf = *(const bf16x8*)(vbase + er * 128 + (((kf * 4 + lk) ^ (er & 7)) << 4));
            yacc[0][ef] = mfma16(pf[0][kf], vf, yacc[0][ef]);
            yacc[1][ef] = mfma16(pf[1][kf], vf, yacc[1][ef]);
          }
        }
      }

      __syncthreads();
    }

#pragma unroll
    for (int qn = 0; qn < 2; qn++) {
      f32x4 rinv;
#pragma unroll
      for (int j = 0; j < 4; j++) rinv[j] = 1.0f / lsum[qn][j];
#pragma unroll
      for (int ef = 0; ef < 4; ef++) {
        int col = h * 64 + ef * 16 + lrow;
#pragma unroll
        for (int j = 0; j < 4; j++) {
          int x = qw + qn * 16 + lk * 4 + j;
          Y[(b * 1024 + x) * 1024 + col] = f2bf(yacc[qn][ef][j] * rinv[j]);
        }
      }
    }
  }
}

// ---------------- launch ----------------
extern "C" void kernel_launch(void* const* d_in, const int* in_sizes, int n_in,
                              void* d_out, int out_size, void* d_ws, size_t ws_size,
                              hipStream_t stream) {
  const float* x  = (const float*)d_in[0];
  const float* z  = (const float*)d_in[1];
  const float* Wq = (const float*)d_in[2];
  const float* bq = (const float*)d_in[3];
  const float* Wk = (const float*)d_in[4];
  const float* bk = (const float*)d_in[5];
  const float* Wv = (const float*)d_in[6];
  const float* bv = (const float*)d_in[7];
  const float* Wp = (const float*)d_in[8];
  const float* bp = (const float*)d_in[9];
  (void)in_sizes; (void)n_in; (void)out_size; (void)ws_size;

  char* ws = (char*)d_ws;
  unsigned short* Xb  = (unsigned short*)(ws + 0);
  unsigned short* Zb  = (unsigned short*)(ws + 16777216);
  unsigned short* Wqt = (unsigned short*)(ws + 33554432);  // Wqt/Wkt/Wvt contiguous = Wqkv
  unsigned short* Wkt = (unsigned short*)(ws + 35651584);
  unsigned short* Wvt = (unsigned short*)(ws + 37748736);
  unsigned short* Wpt = (unsigned short*)(ws + 39845888);
  unsigned short* Qp  = (unsigned short*)(ws + 41943040);
  unsigned short* Kp  = (unsigned short*)(ws + 58720256);
  unsigned short* Vtp = (unsigned short*)(ws + 75497472);

  k_cvt2<<<dim3(2048), dim3(256), 0, stream>>>(x, z, Xb);
  k_pack<<<dim3(16, 16, 4), dim3(256), 0, stream>>>(Wq, Wk, Wv, Wp, Wqt, Wkt, Wvt, Wpt);

  k_gemm_qkv<<<dim3(32, 24), dim3(256), 0, stream>>>(Xb, Zb, Wqt, bq, bk, bv, Qp, Kp, Vtp);

  k_attn<<<dim3(4, 128), dim3(256), 0, stream>>>(Qp, Kp, Vtp, Xb /*Y*/);

  k_gemm<<<dim3(32, 8), dim3(256), 0, stream>>>(Xb, Wpt, bp, d_out, 3, 1.0f);
}

// Round 10
// 169.414 us; speedup vs baseline: 1.0765x; 1.0765x over previous
//
#include <hip/hip_runtime.h>
#include <stdint.h>

// Pipeline: cvt x,z -> bf16; pack weights; fused QKV GEMM (256x128 tile, 128x64/wave,
// 3-slot ring counted-vmcnt, 72KB LDS); flash attention (causal, paired q-blocks,
// 2-phase dbuf); output GEMM -> f32.
// B=8 TX=TZ=1024 DX=DZ=1024 DATT=DMID=64 H=16 DOUT=1024.

typedef float    f32x4  __attribute__((ext_vector_type(4)));
typedef __bf16   bf16x8 __attribute__((ext_vector_type(8)));
typedef unsigned short u16x4 __attribute__((ext_vector_type(4)));
typedef unsigned short u16x8 __attribute__((ext_vector_type(8)));

#define MASKNEG (-3.0e38f)
#define QSCALE_F (0.125f * 1.4426950408889634f)

__device__ __forceinline__ unsigned short f2bf(float f) {
  unsigned int u = __float_as_uint(f);
  u += 0x7fffu + ((u >> 16) & 1u);   // RNE
  return (unsigned short)(u >> 16);
}

__device__ __forceinline__ void gload16(const void* g, void* s) {
  const __attribute__((address_space(1))) unsigned int* gp =
      (const __attribute__((address_space(1))) unsigned int*)(uintptr_t)g;
  __attribute__((address_space(3))) unsigned int* lp =
      (__attribute__((address_space(3))) unsigned int*)(unsigned int)(uintptr_t)s;
  __builtin_amdgcn_global_load_lds(gp, lp, 16, 0, 0);
}

__device__ __forceinline__ f32x4 mfma16(bf16x8 a, bf16x8 b, f32x4 c) {
  return __builtin_amdgcn_mfma_f32_16x16x32_bf16(a, b, c, 0, 0, 0);
}

// ---------------- prep kernels ----------------

__global__ __launch_bounds__(256) void k_cvt2(const float* __restrict__ x,
                                              const float* __restrict__ z,
                                              unsigned short* __restrict__ out) {
  int i = blockIdx.x * 256 + threadIdx.x;
  const int stride = gridDim.x * 256;
  for (; i < 2097152; i += stride) {
    const float* in = (i < 1048576) ? (x + (size_t)i * 8) : (z + (size_t)(i - 1048576) * 8);
    const f32x4* p = (const f32x4*)in;
    f32x4 a = p[0], b = p[1];
    u16x8 o;
    o[0] = f2bf(a[0]); o[1] = f2bf(a[1]); o[2] = f2bf(a[2]); o[3] = f2bf(a[3]);
    o[4] = f2bf(b[0]); o[5] = f2bf(b[1]); o[6] = f2bf(b[2]); o[7] = f2bf(b[3]);
    *(u16x8*)(out + (size_t)i * 8) = o;
  }
}

// All weight packs in one launch, grid (16,16,4).
__global__ __launch_bounds__(256) void k_pack(const float* __restrict__ Wq,
                                              const float* __restrict__ Wk,
                                              const float* __restrict__ Wv,
                                              const float* __restrict__ Wp,
                                              unsigned short* __restrict__ Oq,
                                              unsigned short* __restrict__ Ok,
                                              unsigned short* __restrict__ Ov,
                                              unsigned short* __restrict__ Op) {
  __shared__ float tile[64][65];
  const int t = threadIdx.x;
  const int zid = blockIdx.z;
  if (zid < 3) {
    const float* W = zid == 0 ? Wq : (zid == 1 ? Wk : Wv);
    unsigned short* O = zid == 0 ? Oq : (zid == 1 ? Ok : Ov);
    const int h = blockIdx.x, d0 = blockIdx.y * 64;
    const int ee = t & 63, r0 = t >> 6;
#pragma unroll
    for (int dd = r0; dd < 64; dd += 4)
      tile[dd][ee] = W[(h * 1024 + d0 + dd) * 64 + ee];
    __syncthreads();
    const int d = t & 63, e0 = t >> 6;
#pragma unroll
    for (int e = e0; e < 64; e += 4)
      O[(h * 64 + e) * 1024 + d0 + d] = f2bf(tile[d][e]);
  } else {
    const int k0 = blockIdx.x * 64, n0 = blockIdx.y * 64;
    const int nn = t & 63, r0 = t >> 6;
#pragma unroll
    for (int kk = r0; kk < 64; kk += 4)
      tile[kk][nn] = Wp[(k0 + kk) * 1024 + n0 + nn];
    __syncthreads();
    const int kk = t & 63, e0 = t >> 6;
#pragma unroll
    for (int n2 = e0; n2 < 64; n2 += 4)
      Op[(n0 + n2) * 1024 + k0 + kk] = f2bf(tile[kk][n2]);
  }
}

// ---------------- GEMM body: C[256x128 tile] = A * Bt^T + bias ----------------
// 4 waves, per-wave 128x64 output (acc[8][4]). 3-slot ring, counted vmcnt(6).
// As: 3 slots x 16384 B (256 rows x 64 B). Bs: 3 x 8192 B (128 rows x 64 B).
// Total LDS 72 KB -> 2 blocks/CU. (Round-9 bug: strides/sizes were 2x -> 144 KB.)
// mode 0: bf16 out to [bh][x][64] (Q/K), scaled by oscale
// mode 2: bf16 out to [bh][e][z]  (V transposed)
// mode 3: f32 out, row-major (final projection)
__device__ __forceinline__ void gemm_body(const unsigned short* __restrict__ A,
                                          const unsigned short* __restrict__ Bt,
                                          const float* __restrict__ bias,
                                          void* __restrict__ outp,
                                          int mode, float oscale,
                                          int brow, int bcol,
                                          unsigned short* As, unsigned short* Bs) {
  const int tid = threadIdx.x;
  const int l = tid & 63, w = tid >> 6;
  const int lrow = l & 15, lk = l >> 4;
  const int wr = (w >> 1) * 128, wc = (w & 1) * 64;

  const int arow = tid >> 2;  // 0..63
  const int asrc = ((tid & 3) ^ ((arow >> 1) & 3)) * 8;  // invariant under arow+=64
  const unsigned short* ag0 = A + (size_t)(brow + arow) * 1024 + asrc;
  const unsigned short* bg0 = Bt + (size_t)(bcol + arow) * 1024 + asrc;

  int aoff[8], boff[4];
#pragma unroll
  for (int m = 0; m < 8; m++) {
    int row = wr + m * 16 + lrow;
    aoff[m] = row * 64 + ((lk ^ ((row >> 1) & 3)) << 4);
  }
#pragma unroll
  for (int n = 0; n < 4; n++) {
    int col = wc + n * 16 + lrow;
    boff[n] = col * 64 + ((lk ^ ((col >> 1) & 3)) << 4);
  }

  f32x4 acc[8][4];
#pragma unroll
  for (int n = 0; n < 4; n++) {
    float bv = bias[bcol + wc + n * 16 + lrow];
#pragma unroll
    for (int m = 0; m < 8; m++) acc[m][n] = (f32x4){bv, bv, bv, bv};
  }

  // stage tile kt into ring slot: A 4 x 4KB rounds (rows +64), B 2 rounds. 6 loads.
#define STAGE_G(kt, slot)                                                  \
  {                                                                        \
    char* asb = (char*)As + (slot) * 16384 + w * 1024;                     \
    char* bsb = (char*)Bs + (slot) * 8192 + w * 1024;                      \
    gload16(ag0 + (kt) * 32,          asb);                                \
    gload16(ag0 + (kt) * 32 + 65536,  asb + 4096);                         \
    gload16(ag0 + (kt) * 32 + 131072, asb + 8192);                         \
    gload16(ag0 + (kt) * 32 + 196608, asb + 12288);                        \
    gload16(bg0 + (kt) * 32,          bsb);                                \
    gload16(bg0 + (kt) * 32 + 65536,  bsb + 4096);                         \
  }

  // prologue: tiles 0,1 staged (12 loads); wait tile 0 (6 newest still in flight)
  STAGE_G(0, 0)
  STAGE_G(1, 1)
  asm volatile("s_waitcnt vmcnt(6)" ::: "memory");
  __builtin_amdgcn_s_barrier();
  __builtin_amdgcn_sched_barrier(0);

  int s0 = 0, s2 = 2;
#pragma unroll 1
  for (int kt = 0; kt < 32; kt++) {
    if (kt < 30) STAGE_G(kt + 2, s2)
    const char* ab = (const char*)As + s0 * 16384;
    const char* bb = (const char*)Bs + s0 * 8192;
    bf16x8 bfr[4];
#pragma unroll
    for (int n = 0; n < 4; n++) bfr[n] = *(const bf16x8*)(bb + boff[n]);
#pragma unroll
    for (int m = 0; m < 8; m++) {
      bf16x8 af = *(const bf16x8*)(ab + aoff[m]);
#pragma unroll
      for (int n = 0; n < 4; n++)
        acc[m][n] = mfma16(af, bfr[n], acc[m][n]);
    }
    if (kt < 31) {  // tile kt+1 ready; kt+2's 6 loads stay in flight across barrier
      if (kt < 30) {
        asm volatile("s_waitcnt vmcnt(6)" ::: "memory");
      } else {
        asm volatile("s_waitcnt vmcnt(0)" ::: "memory");
      }
      __builtin_amdgcn_s_barrier();
      __builtin_amdgcn_sched_barrier(0);
    }
    s0 = (s0 == 2) ? 0 : s0 + 1;
    s2 = (s2 == 2) ? 0 : s2 + 1;
  }
#undef STAGE_G

  if (mode == 0) {
    unsigned short* C = (unsigned short*)outp;
#pragma unroll
    for (int m = 0; m < 8; m++) {
      int r = brow + wr + m * 16 + 4 * lk;
#pragma unroll
      for (int n = 0; n < 4; n++) {
        int c = bcol + wc + n * 16 + lrow;
        unsigned short* p = C + ((r >> 10) * 16 + (c >> 6)) * 65536 + (r & 1023) * 64 + (c & 63);
#pragma unroll
        for (int j = 0; j < 4; j++) p[j * 64] = f2bf(acc[m][n][j] * oscale);
      }
    }
  } else if (mode == 2) {
    unsigned short* C = (unsigned short*)outp;
#pragma unroll
    for (int m = 0; m < 8; m++) {
      int r = brow + wr + m * 16 + 4 * lk;
#pragma unroll
      for (int n = 0; n < 4; n++) {
        int c = bcol + wc + n * 16 + lrow;
        u16x4 o;
#pragma unroll
        for (int j = 0; j < 4; j++) o[j] = f2bf(acc[m][n][j]);
        *(u16x4*)(C + ((r >> 10) * 16 + (c >> 6)) * 65536 + (c & 63) * 1024 + (r & 1023)) = o;
      }
    }
  } else {
    float* C = (float*)outp;
#pragma unroll
    for (int m = 0; m < 8; m++) {
      int r = brow + wr + m * 16 + 4 * lk;
#pragma unroll
      for (int n = 0; n < 4; n++) {
        int c = bcol + wc + n * 16 + lrow;
#pragma unroll
        for (int j = 0; j < 4; j++) C[(r + j) * 1024 + c] = acc[m][n][j];
      }
    }
  }
}

// fused QKV: grid (32, 24); y>>3 = segment (0=Q,1=K,2=V), y&7 = col tile (128 wide)
__global__ __launch_bounds__(256, 2) void k_gemm_qkv(const unsigned short* __restrict__ Xb,
                                                     const unsigned short* __restrict__ Zb,
                                                     const unsigned short* __restrict__ Wqkv,
                                                     const float* __restrict__ bq,
                                                     const float* __restrict__ bk,
                                                     const float* __restrict__ bv,
                                                     unsigned short* __restrict__ Qp,
                                                     unsigned short* __restrict__ Kp,
                                                     unsigned short* __restrict__ Vtp) {
  __shared__ unsigned short As[24576];  // 3 slots x 16 KB = 48 KB
  __shared__ unsigned short Bs[12288];  // 3 slots x 8 KB  = 24 KB -> 72 KB total
  const int brow = blockIdx.x * 256;
  const int cg = blockIdx.y;
  const int seg = cg >> 3;
  const int bcol = (cg & 7) * 128;
  const unsigned short* A = (seg == 0) ? Xb : Zb;
  const unsigned short* Bt = Wqkv + (size_t)seg * 1048576;
  const float* bias = (seg == 0) ? bq : (seg == 1 ? bk : bv);
  void* outp = (seg == 0) ? (void*)Qp : (seg == 1 ? (void*)Kp : (void*)Vtp);
  const int mode = (seg == 2) ? 2 : 0;
  const float oscale = (seg == 0) ? QSCALE_F : 1.0f;
  gemm_body(A, Bt, bias, outp, mode, oscale, brow, bcol, As, Bs);
}

// final projection: grid (32, 8), f32 out
__global__ __launch_bounds__(256, 2) void k_gemm(const unsigned short* __restrict__ A,
                                                 const unsigned short* __restrict__ Bt,
                                                 const float* __restrict__ bias,
                                                 void* __restrict__ outp,
                                                 int mode, float oscale) {
  __shared__ unsigned short As[24576];
  __shared__ unsigned short Bs[12288];
  gemm_body(A, Bt, bias, outp, mode, oscale, blockIdx.x * 256, blockIdx.y * 128, As, Bs);
}

// ---------------- flash attention (round-1 orientation, paired q-blocks, 2-phase) ----------------
// (byte-identical to round-7/8 passing version)
__global__ __launch_bounds__(256) void k_attn(const unsigned short* __restrict__ Qh,
                                              const unsigned short* __restrict__ Kh,
                                              const unsigned short* __restrict__ Vth,
                                              unsigned short* __restrict__ Y) {
  __shared__ unsigned short Ks[8192];
  __shared__ unsigned short Vs[8192];
  __shared__ unsigned short Ps[8192];

  const int tid = threadIdx.x, l = tid & 63, w = tid >> 6;
  const int lrow = l & 15, lk = l >> 4;
  const int bh = blockIdx.y;
  const int pp = blockIdx.x;

  const unsigned short* Qb = Qh + bh * 65536;
  const unsigned short* Kb = Kh + bh * 65536;
  const unsigned short* Vb = Vth + bh * 65536;

  bf16x8 ones;
#pragma unroll
  for (int j = 0; j < 8; j++) ones[j] = (__bf16)1.0f;

  const int srow = tid >> 3;
  const int swz = ((tid & 7) ^ (srow & 7)) * 8;
  const unsigned short* kg0 = Kb + srow * 64 + swz;
  const unsigned short* kg1 = Kb + (srow + 32) * 64 + swz;
  const unsigned short* vg0 = Vb + srow * 1024 + swz;
  const unsigned short* vg1 = Vb + (srow + 32) * 1024 + swz;
  char* pw = (char*)Ps + w * 4096;

  const int b = bh >> 4, h = bh & 15;

#pragma unroll 1
  for (int half = 0; half < 2; half++) {
    const int qi = half == 0 ? (7 - pp) : pp;
    const int qw = qi * 128 + w * 32;
    const int qmax = qw + 31;

    bf16x8 qf[2][2];
#pragma unroll
    for (int qn = 0; qn < 2; qn++) {
      const unsigned short* qp = Qb + (qw + qn * 16 + lrow) * 64 + lk * 8;
      qf[qn][0] = *(const bf16x8*)qp;
      qf[qn][1] = *(const bf16x8*)(qp + 32);
    }

    f32x4 m[2], lsum[2], yacc[2][4];
#pragma unroll
    for (int qn = 0; qn < 2; qn++) {
      m[qn] = (f32x4){MASKNEG, MASKNEG, MASKNEG, MASKNEG};
      lsum[qn] = (f32x4){0.f, 0.f, 0.f, 0.f};
#pragma unroll
      for (int ef = 0; ef < 4; ef++) yacc[qn][ef] = (f32x4){0.f, 0.f, 0.f, 0.f};
    }

    const int nt = qi * 2 + 2;

    {
      char* ksb = (char*)Ks + w * 1024;
      char* vsb = (char*)Vs + w * 1024;
      gload16(kg0, ksb);
      gload16(kg1, ksb + 4096);
      gload16(vg0, vsb);
      gload16(vg1, vsb + 4096);
    }
    __syncthreads();

#pragma unroll 1
    for (int t = 0; t < nt; t++) {
      const int z0 = t * 64;
      const int cur = t & 1;
      if (t < nt - 1) {
        const int zn = (t + 1) * 64;
        char* ksb = (char*)Ks + (cur ^ 1) * 8192 + w * 1024;
        char* vsb = (char*)Vs + (cur ^ 1) * 8192 + w * 1024;
        gload16(kg0 + zn * 64, ksb);
        gload16(kg1 + zn * 64, ksb + 4096);
        gload16(vg0 + zn, vsb);
        gload16(vg1 + zn, vsb + 4096);
      }

      if (z0 <= qmax) {
        const char* kbase = (const char*)Ks + cur * 8192;
        const char* vbase = (const char*)Vs + cur * 8192;

        f32x4 s[2][4];
#pragma unroll
        for (int qn = 0; qn < 2; qn++)
#pragma unroll
          for (int zf = 0; zf < 4; zf++) s[qn][zf] = (f32x4){0.f, 0.f, 0.f, 0.f};
#pragma unroll
        for (int zf = 0; zf < 4; zf++) {
          int zr = zf * 16 + lrow;
#pragma unroll
          for (int kf = 0; kf < 2; kf++) {
            bf16x8 kfr = *(const bf16x8*)(kbase + zr * 128 + (((kf * 4 + lk) ^ (zr & 7)) << 4));
            s[0][zf] = mfma16(qf[0][kf], kfr, s[0][zf]);
            s[1][zf] = mfma16(qf[1][kf], kfr, s[1][zf]);
          }
        }

        if (z0 + 63 > qw) {
#pragma unroll
          for (int qn = 0; qn < 2; qn++) {
            int qbase = qw + qn * 16 + 4 * lk;
#pragma unroll
            for (int zf = 0; zf < 4; zf++) {
              int zg = z0 + zf * 16 + lrow;
#pragma unroll
              for (int j = 0; j < 4; j++)
                if (zg > qbase + j) s[qn][zf][j] = MASKNEG;
            }
          }
        }

#pragma unroll
        for (int qn = 0; qn < 2; qn++) {
#pragma unroll
          for (int j = 0; j < 4; j++) {
            float rm = fmaxf(fmaxf(s[qn][0][j], s[qn][1][j]), fmaxf(s[qn][2][j], s[qn][3][j]));
            rm = fmaxf(rm, __shfl_xor(rm, 1));
            rm = fmaxf(rm, __shfl_xor(rm, 2));
            rm = fmaxf(rm, __shfl_xor(rm, 4));
            rm = fmaxf(rm, __shfl_xor(rm, 8));
            float mn = fmaxf(m[qn][j], rm);
            float a = __builtin_amdgcn_exp2f(m[qn][j] - mn);
            m[qn][j] = mn;
            lsum[qn][j] *= a;
#pragma unroll
            for (int ef = 0; ef < 4; ef++) yacc[qn][ef][j] *= a;
#pragma unroll
            for (int zf = 0; zf < 4; zf++)
              s[qn][zf][j] = __builtin_amdgcn_exp2f(s[qn][zf][j] - mn);
          }

#pragma unroll
          for (int zf = 0; zf < 4; zf++) {
            int zc = zf * 16 + lrow;
            int zp = zc >> 3;
#pragma unroll
            for (int j = 0; j < 4; j++) {
              int q = 4 * lk + j;
              *(unsigned short*)(pw + (qn * 16 + q) * 128 + ((zp ^ (q & 7)) << 4) + (zc & 7) * 2)
                  = f2bf(s[qn][zf][j]);
            }
          }
        }

        asm volatile("s_waitcnt lgkmcnt(0)" ::: "memory");
        __builtin_amdgcn_sched_barrier(0);

        bf16x8 pf[2][2];
#pragma unroll
        for (int qn = 0; qn < 2; qn++)
#pragma unroll
          for (int kf = 0; kf < 2; kf++)
            pf[qn][kf] = *(const bf16x8*)(pw + (qn * 16 + lrow) * 128 + (((kf * 4 + lk) ^ (lrow & 7)) << 4));

#pragma unroll
        for (int qn = 0; qn < 2; qn++)
#pragma unroll
          for (int kf = 0; kf < 2; kf++)
            lsum[qn] = mfma16(pf[qn][kf], ones, lsum[qn]);

#pragma unroll
        for (int ef = 0; ef < 4; ef++) {
          int er = ef * 16 + lrow;
#pragma unroll
          for (int kf = 0; kf < 2; kf++) {
            bf16x8 vf = *(const bf16x8*)(vbase + er * 128 + (((kf * 4 + lk) ^ (er & 7)) << 4));
            yacc[0][ef] = mfma16(pf[0][kf], vf, yacc[0][ef]);
            yacc[1][ef] = mfma16(pf[1][kf], vf, yacc[1][ef]);
          }
        }
      }

      __syncthreads();
    }

#pragma unroll
    for (int qn = 0; qn < 2; qn++) {
      f32x4 rinv;
#pragma unroll
      for (int j = 0; j < 4; j++) rinv[j] = 1.0f / lsum[qn][j];
#pragma unroll
      for (int ef = 0; ef < 4; ef++) {
        int col = h * 64 + ef * 16 + lrow;
#pragma unroll
        for (int j = 0; j < 4; j++) {
          int x = qw + qn * 16 + lk * 4 + j;
          Y[(b * 1024 + x) * 1024 + col] = f2bf(yacc[qn][ef][j] * rinv[j]);
        }
      }
    }
  }
}

// ---------------- launch ----------------
extern "C" void kernel_launch(void* const* d_in, const int* in_sizes, int n_in,
                              void* d_out, int out_size, void* d_ws, size_t ws_size,
                              hipStream_t stream) {
  const float* x  = (const float*)d_in[0];
  const float* z  = (const float*)d_in[1];
  const float* Wq = (const float*)d_in[2];
  const float* bq = (const float*)d_in[3];
  const float* Wk = (const float*)d_in[4];
  const float* bk = (const float*)d_in[5];
  const float* Wv = (const float*)d_in[6];
  const float* bv = (const float*)d_in[7];
  const float* Wp = (const float*)d_in[8];
  const float* bp = (const float*)d_in[9];
  (void)in_sizes; (void)n_in; (void)out_size; (void)ws_size;

  char* ws = (char*)d_ws;
  unsigned short* Xb  = (unsigned short*)(ws + 0);
  unsigned short* Zb  = (unsigned short*)(ws + 16777216);
  unsigned short* Wqt = (unsigned short*)(ws + 33554432);  // Wqt/Wkt/Wvt contiguous = Wqkv
  unsigned short* Wkt = (unsigned short*)(ws + 35651584);
  unsigned short* Wvt = (unsigned short*)(ws + 37748736);
  unsigned short* Wpt = (unsigned short*)(ws + 39845888);
  unsigned short* Qp  = (unsigned short*)(ws + 41943040);
  unsigned short* Kp  = (unsigned short*)(ws + 58720256);
  unsigned short* Vtp = (unsigned short*)(ws + 75497472);

  k_cvt2<<<dim3(2048), dim3(256), 0, stream>>>(x, z, Xb);
  k_pack<<<dim3(16, 16, 4), dim3(256), 0, stream>>>(Wq, Wk, Wv, Wp, Wqt, Wkt, Wvt, Wpt);

  k_gemm_qkv<<<dim3(32, 24), dim3(256), 0, stream>>>(Xb, Zb, Wqt, bq, bk, bv, Qp, Kp, Vtp);

  k_attn<<<dim3(4, 128), dim3(256), 0, stream>>>(Qp, Kp, Vtp, Xb /*Y*/);

  k_gemm<<<dim3(32, 8), dim3(256), 0, stream>>>(Xb, Wpt, bp, d_out, 3, 1.0f);
}

// Round 12
// 157.813 us; speedup vs baseline: 1.1557x; 1.0735x over previous
//
#include <hip/hip_runtime.h>
#include <stdint.h>

// Pipeline: cvt x,z -> bf16; pack weights; fused QKV GEMM (256x128 tile, 3-slot ring
// counted-vmcnt, 72KB LDS); flash attention (causal, paired q-blocks, KVBLK=128,
// defer-max); output GEMM -> f32.
// NOTE: v_cvt_pk_bf16_f32 inline asm is BANNED here — correlated with NaN in r2/r3/r11.
// B=8 TX=TZ=1024 DX=DZ=1024 DATT=DMID=64 H=16 DOUT=1024.

typedef float    f32x4  __attribute__((ext_vector_type(4)));
typedef __bf16   bf16x8 __attribute__((ext_vector_type(8)));
typedef unsigned short u16x4 __attribute__((ext_vector_type(4)));
typedef unsigned short u16x8 __attribute__((ext_vector_type(8)));

#define MASKNEG (-3.0e38f)
#define QSCALE_F (0.125f * 1.4426950408889634f)

__device__ __forceinline__ unsigned short f2bf(float f) {
  unsigned int u = __float_as_uint(f);
  u += 0x7fffu + ((u >> 16) & 1u);   // RNE
  return (unsigned short)(u >> 16);
}

__device__ __forceinline__ void gload16(const void* g, void* s) {
  const __attribute__((address_space(1))) unsigned int* gp =
      (const __attribute__((address_space(1))) unsigned int*)(uintptr_t)g;
  __attribute__((address_space(3))) unsigned int* lp =
      (__attribute__((address_space(3))) unsigned int*)(unsigned int)(uintptr_t)s;
  __builtin_amdgcn_global_load_lds(gp, lp, 16, 0, 0);
}

__device__ __forceinline__ f32x4 mfma16(bf16x8 a, bf16x8 b, f32x4 c) {
  return __builtin_amdgcn_mfma_f32_16x16x32_bf16(a, b, c, 0, 0, 0);
}

// ---------------- prep kernels ----------------

__global__ __launch_bounds__(256) void k_cvt2(const float* __restrict__ x,
                                              const float* __restrict__ z,
                                              unsigned short* __restrict__ out) {
  int i = blockIdx.x * 256 + threadIdx.x;
  const int stride = gridDim.x * 256;
  for (; i < 2097152; i += stride) {
    const float* in = (i < 1048576) ? (x + (size_t)i * 8) : (z + (size_t)(i - 1048576) * 8);
    const f32x4* p = (const f32x4*)in;
    f32x4 a = p[0], b = p[1];
    u16x8 o;
    o[0] = f2bf(a[0]); o[1] = f2bf(a[1]); o[2] = f2bf(a[2]); o[3] = f2bf(a[3]);
    o[4] = f2bf(b[0]); o[5] = f2bf(b[1]); o[6] = f2bf(b[2]); o[7] = f2bf(b[3]);
    *(u16x8*)(out + (size_t)i * 8) = o;
  }
}

// All weight packs in one launch, grid (16,16,4).
__global__ __launch_bounds__(256) void k_pack(const float* __restrict__ Wq,
                                              const float* __restrict__ Wk,
                                              const float* __restrict__ Wv,
                                              const float* __restrict__ Wp,
                                              unsigned short* __restrict__ Oq,
                                              unsigned short* __restrict__ Ok,
                                              unsigned short* __restrict__ Ov,
                                              unsigned short* __restrict__ Op) {
  __shared__ float tile[64][65];
  const int t = threadIdx.x;
  const int zid = blockIdx.z;
  if (zid < 3) {
    const float* W = zid == 0 ? Wq : (zid == 1 ? Wk : Wv);
    unsigned short* O = zid == 0 ? Oq : (zid == 1 ? Ok : Ov);
    const int h = blockIdx.x, d0 = blockIdx.y * 64;
    const int ee = t & 63, r0 = t >> 6;
#pragma unroll
    for (int dd = r0; dd < 64; dd += 4)
      tile[dd][ee] = W[(h * 1024 + d0 + dd) * 64 + ee];
    __syncthreads();
    const int d = t & 63, e0 = t >> 6;
#pragma unroll
    for (int e = e0; e < 64; e += 4)
      O[(h * 64 + e) * 1024 + d0 + d] = f2bf(tile[d][e]);
  } else {
    const int k0 = blockIdx.x * 64, n0 = blockIdx.y * 64;
    const int nn = t & 63, r0 = t >> 6;
#pragma unroll
    for (int kk = r0; kk < 64; kk += 4)
      tile[kk][nn] = Wp[(k0 + kk) * 1024 + n0 + nn];
    __syncthreads();
    const int kk = t & 63, e0 = t >> 6;
#pragma unroll
    for (int n2 = e0; n2 < 64; n2 += 4)
      Op[(n0 + n2) * 1024 + k0 + kk] = f2bf(tile[kk][n2]);
  }
}

// ---------------- GEMM body: C[256x128 tile] = A * Bt^T + bias ----------------
// (byte-identical to round-10 passing version)
__device__ __forceinline__ void gemm_body(const unsigned short* __restrict__ A,
                                          const unsigned short* __restrict__ Bt,
                                          const float* __restrict__ bias,
                                          void* __restrict__ outp,
                                          int mode, float oscale,
                                          int brow, int bcol,
                                          unsigned short* As, unsigned short* Bs) {
  const int tid = threadIdx.x;
  const int l = tid & 63, w = tid >> 6;
  const int lrow = l & 15, lk = l >> 4;
  const int wr = (w >> 1) * 128, wc = (w & 1) * 64;

  const int arow = tid >> 2;
  const int asrc = ((tid & 3) ^ ((arow >> 1) & 3)) * 8;
  const unsigned short* ag0 = A + (size_t)(brow + arow) * 1024 + asrc;
  const unsigned short* bg0 = Bt + (size_t)(bcol + arow) * 1024 + asrc;

  int aoff[8], boff[4];
#pragma unroll
  for (int m = 0; m < 8; m++) {
    int row = wr + m * 16 + lrow;
    aoff[m] = row * 64 + ((lk ^ ((row >> 1) & 3)) << 4);
  }
#pragma unroll
  for (int n = 0; n < 4; n++) {
    int col = wc + n * 16 + lrow;
    boff[n] = col * 64 + ((lk ^ ((col >> 1) & 3)) << 4);
  }

  f32x4 acc[8][4];
#pragma unroll
  for (int n = 0; n < 4; n++) {
    float bv = bias[bcol + wc + n * 16 + lrow];
#pragma unroll
    for (int m = 0; m < 8; m++) acc[m][n] = (f32x4){bv, bv, bv, bv};
  }

#define STAGE_G(kt, slot)                                                  \
  {                                                                        \
    char* asb = (char*)As + (slot) * 16384 + w * 1024;                     \
    char* bsb = (char*)Bs + (slot) * 8192 + w * 1024;                      \
    gload16(ag0 + (kt) * 32,          asb);                                \
    gload16(ag0 + (kt) * 32 + 65536,  asb + 4096);                         \
    gload16(ag0 + (kt) * 32 + 131072, asb + 8192);                         \
    gload16(ag0 + (kt) * 32 + 196608, asb + 12288);                        \
    gload16(bg0 + (kt) * 32,          bsb);                                \
    gload16(bg0 + (kt) * 32 + 65536,  bsb + 4096);                         \
  }

  STAGE_G(0, 0)
  STAGE_G(1, 1)
  asm volatile("s_waitcnt vmcnt(6)" ::: "memory");
  __builtin_amdgcn_s_barrier();
  __builtin_amdgcn_sched_barrier(0);

  int s0 = 0, s2 = 2;
#pragma unroll 1
  for (int kt = 0; kt < 32; kt++) {
    if (kt < 30) STAGE_G(kt + 2, s2)
    const char* ab = (const char*)As + s0 * 16384;
    const char* bb = (const char*)Bs + s0 * 8192;
    bf16x8 bfr[4];
#pragma unroll
    for (int n = 0; n < 4; n++) bfr[n] = *(const bf16x8*)(bb + boff[n]);
#pragma unroll
    for (int m = 0; m < 8; m++) {
      bf16x8 af = *(const bf16x8*)(ab + aoff[m]);
#pragma unroll
      for (int n = 0; n < 4; n++)
        acc[m][n] = mfma16(af, bfr[n], acc[m][n]);
    }
    if (kt < 31) {
      if (kt < 30) {
        asm volatile("s_waitcnt vmcnt(6)" ::: "memory");
      } else {
        asm volatile("s_waitcnt vmcnt(0)" ::: "memory");
      }
      __builtin_amdgcn_s_barrier();
      __builtin_amdgcn_sched_barrier(0);
    }
    s0 = (s0 == 2) ? 0 : s0 + 1;
    s2 = (s2 == 2) ? 0 : s2 + 1;
  }
#undef STAGE_G

  if (mode == 0) {
    unsigned short* C = (unsigned short*)outp;
#pragma unroll
    for (int m = 0; m < 8; m++) {
      int r = brow + wr + m * 16 + 4 * lk;
#pragma unroll
      for (int n = 0; n < 4; n++) {
        int c = bcol + wc + n * 16 + lrow;
        unsigned short* p = C + ((r >> 10) * 16 + (c >> 6)) * 65536 + (r & 1023) * 64 + (c & 63);
#pragma unroll
        for (int j = 0; j < 4; j++) p[j * 64] = f2bf(acc[m][n][j] * oscale);
      }
    }
  } else if (mode == 2) {
    unsigned short* C = (unsigned short*)outp;
#pragma unroll
    for (int m = 0; m < 8; m++) {
      int r = brow + wr + m * 16 + 4 * lk;
#pragma unroll
      for (int n = 0; n < 4; n++) {
        int c = bcol + wc + n * 16 + lrow;
        u16x4 o;
#pragma unroll
        for (int j = 0; j < 4; j++) o[j] = f2bf(acc[m][n][j]);
        *(u16x4*)(C + ((r >> 10) * 16 + (c >> 6)) * 65536 + (c & 63) * 1024 + (r & 1023)) = o;
      }
    }
  } else {
    float* C = (float*)outp;
#pragma unroll
    for (int m = 0; m < 8; m++) {
      int r = brow + wr + m * 16 + 4 * lk;
#pragma unroll
      for (int n = 0; n < 4; n++) {
        int c = bcol + wc + n * 16 + lrow;
#pragma unroll
        for (int j = 0; j < 4; j++) C[(r + j) * 1024 + c] = acc[m][n][j];
      }
    }
  }
}

__global__ __launch_bounds__(256, 2) void k_gemm_qkv(const unsigned short* __restrict__ Xb,
                                                     const unsigned short* __restrict__ Zb,
                                                     const unsigned short* __restrict__ Wqkv,
                                                     const float* __restrict__ bq,
                                                     const float* __restrict__ bk,
                                                     const float* __restrict__ bv,
                                                     unsigned short* __restrict__ Qp,
                                                     unsigned short* __restrict__ Kp,
                                                     unsigned short* __restrict__ Vtp) {
  __shared__ unsigned short As[24576];
  __shared__ unsigned short Bs[12288];
  const int brow = blockIdx.x * 256;
  const int cg = blockIdx.y;
  const int seg = cg >> 3;
  const int bcol = (cg & 7) * 128;
  const unsigned short* A = (seg == 0) ? Xb : Zb;
  const unsigned short* Bt = Wqkv + (size_t)seg * 1048576;
  const float* bias = (seg == 0) ? bq : (seg == 1 ? bk : bv);
  void* outp = (seg == 0) ? (void*)Qp : (seg == 1 ? (void*)Kp : (void*)Vtp);
  const int mode = (seg == 2) ? 2 : 0;
  const float oscale = (seg == 0) ? QSCALE_F : 1.0f;
  gemm_body(A, Bt, bias, outp, mode, oscale, brow, bcol, As, Bs);
}

__global__ __launch_bounds__(256, 2) void k_gemm(const unsigned short* __restrict__ A,
                                                 const unsigned short* __restrict__ Bt,
                                                 const float* __restrict__ bias,
                                                 void* __restrict__ outp,
                                                 int mode, float oscale) {
  __shared__ unsigned short As[24576];
  __shared__ unsigned short Bs[12288];
  gemm_body(A, Bt, bias, outp, mode, oscale, blockIdx.x * 256, blockIdx.y * 128, As, Bs);
}

// ---------------- flash attention: KVBLK=128, defer-max (scalar f2bf P-cvt) ----------------
// Q [bh][1024][64] (prescaled), K [bh][1024][64], Vt [bh][64][1024] -> Y bf16. Causal.
// Block handles q-blocks qi=7-pp then qi=pp (9 KV-tiles of 128 total -> balanced).
// 4 waves x 32 q. S = mfma(Qfrag, Kfrag) (round-1 validated orientation).
// Softmax once per 128 z; P-write/PV in two 64-z halves (Ps stays 16 KB).
__global__ __launch_bounds__(256, 2) void k_attn(const unsigned short* __restrict__ Qh,
                                                 const unsigned short* __restrict__ Kh,
                                                 const unsigned short* __restrict__ Vth,
                                                 unsigned short* __restrict__ Y) {
  __shared__ unsigned short Ks[16384];  // 2 x (128 z x 64 d) swizzled, 32 KB
  __shared__ unsigned short Vs[16384];  // 2 x (64 e x 128 z) swizzled, 32 KB
  __shared__ unsigned short Ps[8192];   // 4 waves x (32 q x 64 z) swizzled, 16 KB

  const int tid = threadIdx.x, l = tid & 63, w = tid >> 6;
  const int lrow = l & 15, lk = l >> 4;
  const int bh = blockIdx.y;
  const int pp = blockIdx.x;

  const unsigned short* Qb = Qh + bh * 65536;
  const unsigned short* Kb = Kh + bh * 65536;
  const unsigned short* Vb = Vth + bh * 65536;

  bf16x8 ones;
#pragma unroll
  for (int j = 0; j < 8; j++) ones[j] = (__bf16)1.0f;

  // K staging: wave w stages rows w*32 + c*8 + (l>>3), c=0..3; source pre-swizzled.
  const int krl = l >> 3;
  const int kgp = l & 7;
  const unsigned short* kgsrc = Kb + (w * 32 + krl) * 64 + ((kgp ^ krl) * 8);
  // V staging: wave w stages rows w*16 + c*4 + (l>>4); XOR depends on c -> 4 bases.
  const int vrl = l >> 4;
  const int vgp = l & 15;
  const int vr0 = w * 16 + 0 * 4 + vrl;
  const int vr1 = w * 16 + 1 * 4 + vrl;
  const int vr2 = w * 16 + 2 * 4 + vrl;
  const int vr3 = w * 16 + 3 * 4 + vrl;
  const int voff0 = vr0 * 1024 + ((vgp ^ (vr0 & 15)) * 8);
  const int voff1 = vr1 * 1024 + ((vgp ^ (vr1 & 15)) * 8);
  const int voff2 = vr2 * 1024 + ((vgp ^ (vr2 & 15)) * 8);
  const int voff3 = vr3 * 1024 + ((vgp ^ (vr3 & 15)) * 8);

  char* pw = (char*)Ps + w * 4096;

  const int b = bh >> 4, h = bh & 15;

#pragma unroll 1
  for (int hp = 0; hp < 2; hp++) {
    const int qi = hp == 0 ? (7 - pp) : pp;
    const int qw = qi * 128 + w * 32;
    const int qmax = qw + 31;

    bf16x8 qf[2][2];
#pragma unroll
    for (int qn = 0; qn < 2; qn++) {
      const unsigned short* qp = Qb + (qw + qn * 16 + lrow) * 64 + lk * 8;
      qf[qn][0] = *(const bf16x8*)qp;
      qf[qn][1] = *(const bf16x8*)(qp + 32);
    }

    f32x4 m[2], lsum[2], yacc[2][4];
#pragma unroll
    for (int qn = 0; qn < 2; qn++) {
      m[qn] = (f32x4){MASKNEG, MASKNEG, MASKNEG, MASKNEG};
      lsum[qn] = (f32x4){0.f, 0.f, 0.f, 0.f};
#pragma unroll
      for (int ef = 0; ef < 4; ef++) yacc[qn][ef] = (f32x4){0.f, 0.f, 0.f, 0.f};
    }

    const int nt = qi + 1;   // tiles of 128 z

    // prologue: stage tile 0 into buffer 0
    {
      char* kb = (char*)Ks + w * 4096;
      char* vb2 = (char*)Vs + w * 4096;
      gload16(kgsrc + 0,    kb);
      gload16(kgsrc + 512,  kb + 1024);
      gload16(kgsrc + 1024, kb + 2048);
      gload16(kgsrc + 1536, kb + 3072);
      gload16(Vb + voff0, vb2);
      gload16(Vb + voff1, vb2 + 1024);
      gload16(Vb + voff2, vb2 + 2048);
      gload16(Vb + voff3, vb2 + 3072);
    }
    __syncthreads();

#pragma unroll 1
    for (int t = 0; t < nt; t++) {
      const int z0 = t * 128;
      const int cur = t & 1;
      if (t < nt - 1) {
        const int zn = (t + 1) * 128;
        char* kb = (char*)Ks + (cur ^ 1) * 16384 + w * 4096;
        char* vb2 = (char*)Vs + (cur ^ 1) * 16384 + w * 4096;
        const unsigned short* kgt = kgsrc + zn * 64;
        gload16(kgt + 0,    kb);
        gload16(kgt + 512,  kb + 1024);
        gload16(kgt + 1024, kb + 2048);
        gload16(kgt + 1536, kb + 3072);
        gload16(Vb + voff0 + zn, vb2);
        gload16(Vb + voff1 + zn, vb2 + 1024);
        gload16(Vb + voff2 + zn, vb2 + 2048);
        gload16(Vb + voff3 + zn, vb2 + 3072);
      }

      if (z0 <= qmax) {
        const char* kbase = (const char*)Ks + cur * 16384;
        const char* vbase = (const char*)Vs + cur * 16384;

        // S: lane holds S[q = qw + qn*16 + lk*4 + j][z = z0 + zf*16 + lrow], zf 0..7
        f32x4 s[2][8];
#pragma unroll
        for (int qn = 0; qn < 2; qn++)
#pragma unroll
          for (int zf = 0; zf < 8; zf++) s[qn][zf] = (f32x4){0.f, 0.f, 0.f, 0.f};
#pragma unroll
        for (int zf = 0; zf < 8; zf++) {
          int zr = zf * 16 + lrow;
#pragma unroll
          for (int kf = 0; kf < 2; kf++) {
            bf16x8 kfr = *(const bf16x8*)(kbase + zr * 128 + (((kf * 4 + lk) ^ (zr & 7)) << 4));
            s[0][zf] = mfma16(qf[0][kf], kfr, s[0][zf]);
            s[1][zf] = mfma16(qf[1][kf], kfr, s[1][zf]);
          }
        }

        if (z0 + 127 > qw) {   // diagonal overlap: mask z > q
#pragma unroll
          for (int qn = 0; qn < 2; qn++) {
            int qbase = qw + qn * 16 + 4 * lk;
#pragma unroll
            for (int zf = 0; zf < 8; zf++) {
              int zg = z0 + zf * 16 + lrow;
#pragma unroll
              for (int j = 0; j < 4; j++)
                if (zg > qbase + j) s[qn][zf][j] = MASKNEG;
            }
          }
        }

        // softmax once per 128 z: in-lane max over 8 zf + 4 shfls; defer-max THR=8
#pragma unroll
        for (int qn = 0; qn < 2; qn++) {
          f32x4 rm4 = s[qn][0];
#pragma unroll
          for (int zf = 1; zf < 8; zf++)
#pragma unroll
            for (int j = 0; j < 4; j++) rm4[j] = fmaxf(rm4[j], s[qn][zf][j]);
#pragma unroll
          for (int j = 0; j < 4; j++) {
            float r = rm4[j];
            r = fmaxf(r, __shfl_xor(r, 1));
            r = fmaxf(r, __shfl_xor(r, 2));
            r = fmaxf(r, __shfl_xor(r, 4));
            r = fmaxf(r, __shfl_xor(r, 8));
            rm4[j] = r;
          }
          int trig = (rm4[0] > m[qn][0] + 8.f) | (rm4[1] > m[qn][1] + 8.f) |
                     (rm4[2] > m[qn][2] + 8.f) | (rm4[3] > m[qn][3] + 8.f);
          if (__any(trig)) {
#pragma unroll
            for (int j = 0; j < 4; j++) {
              float mn = fmaxf(m[qn][j], rm4[j]);
              float a = __builtin_amdgcn_exp2f(m[qn][j] - mn);
              m[qn][j] = mn;
              lsum[qn][j] *= a;
#pragma unroll
              for (int ef = 0; ef < 4; ef++) yacc[qn][ef][j] *= a;
            }
          }
#pragma unroll
          for (int zf = 0; zf < 8; zf++)
#pragma unroll
            for (int j = 0; j < 4; j++)
              s[qn][zf][j] = __builtin_amdgcn_exp2f(s[qn][zf][j] - m[qn][j]);  // <= 2^8
        }

        // PV in two 64-z halves (Ps buffer reused; per-wave private)
#pragma unroll
        for (int hf = 0; hf < 2; hf++) {
          if (z0 + hf * 64 <= qmax) {
            // P -> per-wave LDS (bf16, round-4-validated scalar f2bf + swizzle)
#pragma unroll
            for (int qn = 0; qn < 2; qn++) {
#pragma unroll
              for (int zf2 = 0; zf2 < 4; zf2++) {
                int zfg = hf * 4 + zf2;
                int zc = zf2 * 16 + lrow;
                int zp = zc >> 3;
#pragma unroll
                for (int j = 0; j < 4; j++) {
                  int q = 4 * lk + j;
                  *(unsigned short*)(pw + (qn * 16 + q) * 128 + ((zp ^ (q & 7)) << 4) + (zc & 7) * 2)
                      = f2bf(s[qn][zfg][j]);
                }
              }
            }

            asm volatile("s_waitcnt lgkmcnt(0)" ::: "memory");
            __builtin_amdgcn_sched_barrier(0);

            bf16x8 pf[2][2];
#pragma unroll
            for (int qn = 0; qn < 2; qn++)
#pragma unroll
              for (int kf = 0; kf < 2; kf++)
                pf[qn][kf] = *(const bf16x8*)(pw + (qn * 16 + lrow) * 128 + (((kf * 4 + lk) ^ (lrow & 7)) << 4));

#pragma unroll
            for (int qn = 0; qn < 2; qn++)
#pragma unroll
              for (int kf = 0; kf < 2; kf++)
                lsum[qn] = mfma16(pf[qn][kf], ones, lsum[qn]);

#pragma unroll
            for (int ef = 0; ef < 4; ef++) {
              int er = ef * 16 + lrow;
#pragma unroll
              for (int kf = 0; kf < 2; kf++) {
                int g = hf * 8 + kf * 4 + lk;
                bf16x8 vf = *(const bf16x8*)(vbase + er * 256 + ((g ^ (er & 15)) << 4));
                yacc[0][ef] = mfma16(pf[0][kf], vf, yacc[0][ef]);
                yacc[1][ef] = mfma16(pf[1][kf], vf, yacc[1][ef]);
              }
            }
          }
        }
      }

      __syncthreads();   // Ks/Vs dbuf handoff
    }

    // epilogue: Y[q][e] = yacc / lsum ; q = qw + qn*16 + lk*4 + j, e = ef*16 + lrow
#pragma unroll
    for (int qn = 0; qn < 2; qn++) {
      f32x4 rinv;
#pragma unroll
      for (int j = 0; j < 4; j++) rinv[j] = 1.0f / lsum[qn][j];
#pragma unroll
      for (int ef = 0; ef < 4; ef++) {
        int col = h * 64 + ef * 16 + lrow;
#pragma unroll
        for (int j = 0; j < 4; j++) {
          int x = qw + qn * 16 + lk * 4 + j;
          Y[(b * 1024 + x) * 1024 + col] = f2bf(yacc[qn][ef][j] * rinv[j]);
        }
      }
    }
  }
}

// ---------------- launch ----------------
extern "C" void kernel_launch(void* const* d_in, const int* in_sizes, int n_in,
                              void* d_out, int out_size, void* d_ws, size_t ws_size,
                              hipStream_t stream) {
  const float* x  = (const float*)d_in[0];
  const float* z  = (const float*)d_in[1];
  const float* Wq = (const float*)d_in[2];
  const float* bq = (const float*)d_in[3];
  const float* Wk = (const float*)d_in[4];
  const float* bk = (const float*)d_in[5];
  const float* Wv = (const float*)d_in[6];
  const float* bv = (const float*)d_in[7];
  const float* Wp = (const float*)d_in[8];
  const float* bp = (const float*)d_in[9];
  (void)in_sizes; (void)n_in; (void)out_size; (void)ws_size;

  char* ws = (char*)d_ws;
  unsigned short* Xb  = (unsigned short*)(ws + 0);
  unsigned short* Zb  = (unsigned short*)(ws + 16777216);
  unsigned short* Wqt = (unsigned short*)(ws + 33554432);  // Wqt/Wkt/Wvt contiguous = Wqkv
  unsigned short* Wkt = (unsigned short*)(ws + 35651584);
  unsigned short* Wvt = (unsigned short*)(ws + 37748736);
  unsigned short* Wpt = (unsigned short*)(ws + 39845888);
  unsigned short* Qp  = (unsigned short*)(ws + 41943040);
  unsigned short* Kp  = (unsigned short*)(ws + 58720256);
  unsigned short* Vtp = (unsigned short*)(ws + 75497472);

  k_cvt2<<<dim3(2048), dim3(256), 0, stream>>>(x, z, Xb);
  k_pack<<<dim3(16, 16, 4), dim3(256), 0, stream>>>(Wq, Wk, Wv, Wp, Wqt, Wkt, Wvt, Wpt);

  k_gemm_qkv<<<dim3(32, 24), dim3(256), 0, stream>>>(Xb, Zb, Wqt, bq, bk, bv, Qp, Kp, Vtp);

  k_attn<<<dim3(4, 128), dim3(256), 0, stream>>>(Qp, Kp, Vtp, Xb /*Y*/);

  k_gemm<<<dim3(32, 8), dim3(256), 0, stream>>>(Xb, Wpt, bp, d_out, 3, 1.0f);
}

// Round 13
// 156.774 us; speedup vs baseline: 1.1633x; 1.0066x over previous
//
#include <hip/hip_runtime.h>
#include <stdint.h>

// Pipeline: cvt x,z -> bf16; pack weights; fused QKV GEMM (128x128 tile, BK=64,
// 4-phase counted-vmcnt schedule, 64KB LDS); flash attention (causal, KVBLK=128,
// defer-max); output GEMM -> f32.
// v_cvt_pk_bf16_f32 inline asm is BANNED (NaN culprit, r2/r3/r11 vs r12).
// B=8 TX=TZ=1024 DX=DZ=1024 DATT=DMID=64 H=16 DOUT=1024.

typedef float    f32x4  __attribute__((ext_vector_type(4)));
typedef __bf16   bf16x8 __attribute__((ext_vector_type(8)));
typedef unsigned short u16x4 __attribute__((ext_vector_type(4)));
typedef unsigned short u16x8 __attribute__((ext_vector_type(8)));

#define MASKNEG (-3.0e38f)
#define QSCALE_F (0.125f * 1.4426950408889634f)

__device__ __forceinline__ unsigned short f2bf(float f) {
  unsigned int u = __float_as_uint(f);
  u += 0x7fffu + ((u >> 16) & 1u);   // RNE
  return (unsigned short)(u >> 16);
}

__device__ __forceinline__ void gload16(const void* g, void* s) {
  const __attribute__((address_space(1))) unsigned int* gp =
      (const __attribute__((address_space(1))) unsigned int*)(uintptr_t)g;
  __attribute__((address_space(3))) unsigned int* lp =
      (__attribute__((address_space(3))) unsigned int*)(unsigned int)(uintptr_t)s;
  __builtin_amdgcn_global_load_lds(gp, lp, 16, 0, 0);
}

__device__ __forceinline__ f32x4 mfma16(bf16x8 a, bf16x8 b, f32x4 c) {
  return __builtin_amdgcn_mfma_f32_16x16x32_bf16(a, b, c, 0, 0, 0);
}

// ---------------- prep kernels (r12 verbatim) ----------------

__global__ __launch_bounds__(256) void k_cvt2(const float* __restrict__ x,
                                              const float* __restrict__ z,
                                              unsigned short* __restrict__ out) {
  int i = blockIdx.x * 256 + threadIdx.x;
  const int stride = gridDim.x * 256;
  for (; i < 2097152; i += stride) {
    const float* in = (i < 1048576) ? (x + (size_t)i * 8) : (z + (size_t)(i - 1048576) * 8);
    const f32x4* p = (const f32x4*)in;
    f32x4 a = p[0], b = p[1];
    u16x8 o;
    o[0] = f2bf(a[0]); o[1] = f2bf(a[1]); o[2] = f2bf(a[2]); o[3] = f2bf(a[3]);
    o[4] = f2bf(b[0]); o[5] = f2bf(b[1]); o[6] = f2bf(b[2]); o[7] = f2bf(b[3]);
    *(u16x8*)(out + (size_t)i * 8) = o;
  }
}

__global__ __launch_bounds__(256) void k_pack(const float* __restrict__ Wq,
                                              const float* __restrict__ Wk,
                                              const float* __restrict__ Wv,
                                              const float* __restrict__ Wp,
                                              unsigned short* __restrict__ Oq,
                                              unsigned short* __restrict__ Ok,
                                              unsigned short* __restrict__ Ov,
                                              unsigned short* __restrict__ Op) {
  __shared__ float tile[64][65];
  const int t = threadIdx.x;
  const int zid = blockIdx.z;
  if (zid < 3) {
    const float* W = zid == 0 ? Wq : (zid == 1 ? Wk : Wv);
    unsigned short* O = zid == 0 ? Oq : (zid == 1 ? Ok : Ov);
    const int h = blockIdx.x, d0 = blockIdx.y * 64;
    const int ee = t & 63, r0 = t >> 6;
#pragma unroll
    for (int dd = r0; dd < 64; dd += 4)
      tile[dd][ee] = W[(h * 1024 + d0 + dd) * 64 + ee];
    __syncthreads();
    const int d = t & 63, e0 = t >> 6;
#pragma unroll
    for (int e = e0; e < 64; e += 4)
      O[(h * 64 + e) * 1024 + d0 + d] = f2bf(tile[d][e]);
  } else {
    const int k0 = blockIdx.x * 64, n0 = blockIdx.y * 64;
    const int nn = t & 63, r0 = t >> 6;
#pragma unroll
    for (int kk = r0; kk < 64; kk += 4)
      tile[kk][nn] = Wp[(k0 + kk) * 1024 + n0 + nn];
    __syncthreads();
    const int kk = t & 63, e0 = t >> 6;
#pragma unroll
    for (int n2 = e0; n2 < 64; n2 += 4)
      Op[(n0 + n2) * 1024 + k0 + kk] = f2bf(tile[kk][n2]);
  }
}

// ---------------- GEMM body: 4-phase counted-vmcnt, 128x128 tile, BK=64 ----------------
// LDS: A = 2dbuf x 2 k-planes x [128 rows][32 k] (8 KB each) = 32 KB; B same; 64 KB total.
// Per K-tile (BK=64), 4 phases (kh, nh): each = vmcnt/barrier, ds_read frags,
// stage next tile's plane-pair (at kh boundaries), 8 MFMA under setprio.
// Planes staged exactly 4 phases before first read -> steady-state vmcnt(4).
// Swizzle: 64B rows, granule lk ^ ((row>>1)&3) (r12-validated, conflict-free).
// mode 0: bf16 out [bh][x][64] (Q/K) scaled; mode 2: bf16 [bh][e][z] (V^T); mode 3: f32.
__device__ __forceinline__ void gemm_body(const unsigned short* __restrict__ A,
                                          const unsigned short* __restrict__ Bt,
                                          const float* __restrict__ bias,
                                          void* __restrict__ outp,
                                          int mode, float oscale,
                                          int brow, int bcol,
                                          unsigned short* As, unsigned short* Bs) {
  const int tid = threadIdx.x;
  const int l = tid & 63, w = tid >> 6;
  const int lrow = l & 15, lk = l >> 4;
  const int wr = (w >> 1) * 64, wc = (w & 1) * 64;

  // staging: lane writes plane slot (i*4+w)*1024B + l*16B -> row (i*4+w)*16 + (l>>2),
  // dest granule l&3; source k-granule pre-swizzled: (l&3) ^ ((l>>3)&3).
  const int gsrc = ((l & 3) ^ ((l >> 3) & 3)) * 8;
  const int srow = (l >> 2);
  const unsigned short* agp0 = A + (size_t)(brow + w * 16 + srow) * 1024 + gsrc;
  const unsigned short* agp1 = agp0 + (size_t)64 * 1024;
  const unsigned short* bgp0 = Bt + (size_t)(bcol + w * 16 + srow) * 1024 + gsrc;
  const unsigned short* bgp1 = bgp0 + (size_t)64 * 1024;

  // frag read byte-offsets within a k-plane
  int aoff[4], boff[4];
#pragma unroll
  for (int m = 0; m < 4; m++) {
    int row = wr + m * 16 + lrow;
    aoff[m] = row * 64 + ((lk ^ ((lrow >> 1) & 3)) << 4);
  }
#pragma unroll
  for (int n = 0; n < 4; n++) {
    int col = wc + n * 16 + lrow;
    boff[n] = col * 64 + ((lk ^ ((lrow >> 1) & 3)) << 4);
  }

  f32x4 acc[4][4];
#pragma unroll
  for (int n = 0; n < 4; n++) {
    float bv = bias[bcol + wc + n * 16 + lrow];
#pragma unroll
    for (int m = 0; m < 4; m++) acc[m][n] = (f32x4){bv, bv, bv, bv};
  }

  // stage one kh-plane-pair (A+B) of tile kt into dbuf db: 4 gloads/thread
#define STAGE_KH(kt, kh, db)                                               \
  {                                                                        \
    char* ab = (char*)As + (db) * 16384 + (kh) * 8192 + w * 1024;          \
    char* bb = (char*)Bs + (db) * 16384 + (kh) * 8192 + w * 1024;          \
    gload16(agp0 + (kt) * 64 + (kh) * 32, ab);                             \
    gload16(agp1 + (kt) * 64 + (kh) * 32, ab + 4096);                      \
    gload16(bgp0 + (kt) * 64 + (kh) * 32, bb);                             \
    gload16(bgp1 + (kt) * 64 + (kh) * 32, bb + 4096);                      \
  }

  // prologue: stage tile 0 fully (kh0 then kh1; 8 loads in flight, FIFO)
  STAGE_KH(0, 0, 0)
  STAGE_KH(0, 1, 0)

#pragma unroll 1
  for (int kt = 0; kt < 16; kt++) {
    const int db = kt & 1;
    const char* abase = (const char*)As + db * 16384;
    const char* bbase = (const char*)Bs + db * 16384;
    bf16x8 afr[4], bfr[2];

    // ---- phase 0: kh=0, n in {0,1}; drains this tile's kh0 planes ----
    asm volatile("s_waitcnt vmcnt(4)" ::: "memory");
    __builtin_amdgcn_s_barrier();
    __builtin_amdgcn_sched_barrier(0);
#pragma unroll
    for (int m = 0; m < 4; m++) afr[m] = *(const bf16x8*)(abase + aoff[m]);
    bfr[0] = *(const bf16x8*)(bbase + boff[0]);
    bfr[1] = *(const bf16x8*)(bbase + boff[1]);
    if (kt < 15) STAGE_KH(kt + 1, 0, db ^ 1)
    __builtin_amdgcn_s_setprio(1);
#pragma unroll
    for (int m = 0; m < 4; m++) {
      acc[m][0] = mfma16(afr[m], bfr[0], acc[m][0]);
      acc[m][1] = mfma16(afr[m], bfr[1], acc[m][1]);
    }
    __builtin_amdgcn_s_setprio(0);

    // ---- phase 1: kh=0, n in {2,3} (A frags reused) ----
    asm volatile("" ::: "memory");
    __builtin_amdgcn_s_barrier();
    __builtin_amdgcn_sched_barrier(0);
    bfr[0] = *(const bf16x8*)(bbase + boff[2]);
    bfr[1] = *(const bf16x8*)(bbase + boff[3]);
    __builtin_amdgcn_s_setprio(1);
#pragma unroll
    for (int m = 0; m < 4; m++) {
      acc[m][2] = mfma16(afr[m], bfr[0], acc[m][2]);
      acc[m][3] = mfma16(afr[m], bfr[1], acc[m][3]);
    }
    __builtin_amdgcn_s_setprio(0);

    // ---- phase 2: kh=1, n in {0,1}; drains this tile's kh1 planes ----
    if (kt < 15) {
      asm volatile("s_waitcnt vmcnt(4)" ::: "memory");
    } else {
      asm volatile("s_waitcnt vmcnt(0)" ::: "memory");
    }
    __builtin_amdgcn_s_barrier();
    __builtin_amdgcn_sched_barrier(0);
#pragma unroll
    for (int m = 0; m < 4; m++) afr[m] = *(const bf16x8*)(abase + 8192 + aoff[m]);
    bfr[0] = *(const bf16x8*)(bbase + 8192 + boff[0]);
    bfr[1] = *(const bf16x8*)(bbase + 8192 + boff[1]);
    if (kt < 15) STAGE_KH(kt + 1, 1, db ^ 1)
    __builtin_amdgcn_s_setprio(1);
#pragma unroll
    for (int m = 0; m < 4; m++) {
      acc[m][0] = mfma16(afr[m], bfr[0], acc[m][0]);
      acc[m][1] = mfma16(afr[m], bfr[1], acc[m][1]);
    }
    __builtin_amdgcn_s_setprio(0);

    // ---- phase 3: kh=1, n in {2,3} ----
    asm volatile("" ::: "memory");
    __builtin_amdgcn_s_barrier();
    __builtin_amdgcn_sched_barrier(0);
    bfr[0] = *(const bf16x8*)(bbase + 8192 + boff[2]);
    bfr[1] = *(const bf16x8*)(bbase + 8192 + boff[3]);
    __builtin_amdgcn_s_setprio(1);
#pragma unroll
    for (int m = 0; m < 4; m++) {
      acc[m][2] = mfma16(afr[m], bfr[0], acc[m][2]);
      acc[m][3] = mfma16(afr[m], bfr[1], acc[m][3]);
    }
    __builtin_amdgcn_s_setprio(0);
  }
#undef STAGE_KH

  // epilogue (r7-validated, acc[4][4], wave tile 64x64)
  if (mode == 0) {
    unsigned short* C = (unsigned short*)outp;
#pragma unroll
    for (int m = 0; m < 4; m++) {
      int r = brow + wr + m * 16 + 4 * lk;
#pragma unroll
      for (int n = 0; n < 4; n++) {
        int c = bcol + wc + n * 16 + lrow;
        unsigned short* p = C + ((r >> 10) * 16 + (c >> 6)) * 65536 + (r & 1023) * 64 + (c & 63);
#pragma unroll
        for (int j = 0; j < 4; j++) p[j * 64] = f2bf(acc[m][n][j] * oscale);
      }
    }
  } else if (mode == 2) {
    unsigned short* C = (unsigned short*)outp;
#pragma unroll
    for (int m = 0; m < 4; m++) {
      int r = brow + wr + m * 16 + 4 * lk;
#pragma unroll
      for (int n = 0; n < 4; n++) {
        int c = bcol + wc + n * 16 + lrow;
        u16x4 o;
#pragma unroll
        for (int j = 0; j < 4; j++) o[j] = f2bf(acc[m][n][j]);
        *(u16x4*)(C + ((r >> 10) * 16 + (c >> 6)) * 65536 + (c & 63) * 1024 + (r & 1023)) = o;
      }
    }
  } else {
    float* C = (float*)outp;
#pragma unroll
    for (int m = 0; m < 4; m++) {
      int r = brow + wr + m * 16 + 4 * lk;
#pragma unroll
      for (int n = 0; n < 4; n++) {
        int c = bcol + wc + n * 16 + lrow;
#pragma unroll
        for (int j = 0; j < 4; j++) C[(r + j) * 1024 + c] = acc[m][n][j];
      }
    }
  }
}

// fused QKV: grid (64, 24); y>>3 = segment (0=Q,1=K,2=V), y&7 = col tile
__global__ __launch_bounds__(256, 2) void k_gemm_qkv(const unsigned short* __restrict__ Xb,
                                                     const unsigned short* __restrict__ Zb,
                                                     const unsigned short* __restrict__ Wqkv,
                                                     const float* __restrict__ bq,
                                                     const float* __restrict__ bk,
                                                     const float* __restrict__ bv,
                                                     unsigned short* __restrict__ Qp,
                                                     unsigned short* __restrict__ Kp,
                                                     unsigned short* __restrict__ Vtp) {
  __shared__ unsigned short As[16384];  // 32 KB
  __shared__ unsigned short Bs[16384];  // 32 KB -> 64 KB total
  const int brow = blockIdx.x * 128;
  const int cg = blockIdx.y;
  const int seg = cg >> 3;
  const int bcol = (cg & 7) * 128;
  const unsigned short* A = (seg == 0) ? Xb : Zb;
  const unsigned short* Bt = Wqkv + (size_t)seg * 1048576;
  const float* bias = (seg == 0) ? bq : (seg == 1 ? bk : bv);
  void* outp = (seg == 0) ? (void*)Qp : (seg == 1 ? (void*)Kp : (void*)Vtp);
  const int mode = (seg == 2) ? 2 : 0;
  const float oscale = (seg == 0) ? QSCALE_F : 1.0f;
  gemm_body(A, Bt, bias, outp, mode, oscale, brow, bcol, As, Bs);
}

// final projection: grid (64, 8), f32 out
__global__ __launch_bounds__(256, 2) void k_gemm(const unsigned short* __restrict__ A,
                                                 const unsigned short* __restrict__ Bt,
                                                 const float* __restrict__ bias,
                                                 void* __restrict__ outp,
                                                 int mode, float oscale) {
  __shared__ unsigned short As[16384];
  __shared__ unsigned short Bs[16384];
  gemm_body(A, Bt, bias, outp, mode, oscale, blockIdx.x * 128, blockIdx.y * 128, As, Bs);
}

// ---------------- flash attention (r12 verbatim): KVBLK=128, defer-max ----------------
__global__ __launch_bounds__(256, 2) void k_attn(const unsigned short* __restrict__ Qh,
                                                 const unsigned short* __restrict__ Kh,
                                                 const unsigned short* __restrict__ Vth,
                                                 unsigned short* __restrict__ Y) {
  __shared__ unsigned short Ks[16384];
  __shared__ unsigned short Vs[16384];
  __shared__ unsigned short Ps[8192];

  const int tid = threadIdx.x, l = tid & 63, w = tid >> 6;
  const int lrow = l & 15, lk = l >> 4;
  const int bh = blockIdx.y;
  const int pp = blockIdx.x;

  const unsigned short* Qb = Qh + bh * 65536;
  const unsigned short* Kb = Kh + bh * 65536;
  const unsigned short* Vb = Vth + bh * 65536;

  bf16x8 ones;
#pragma unroll
  for (int j = 0; j < 8; j++) ones[j] = (__bf16)1.0f;

  const int krl = l >> 3;
  const int kgp = l & 7;
  const unsigned short* kgsrc = Kb + (w * 32 + krl) * 64 + ((kgp ^ krl) * 8);
  const int vrl = l >> 4;
  const int vgp = l & 15;
  const int vr0 = w * 16 + 0 * 4 + vrl;
  const int vr1 = w * 16 + 1 * 4 + vrl;
  const int vr2 = w * 16 + 2 * 4 + vrl;
  const int vr3 = w * 16 + 3 * 4 + vrl;
  const int voff0 = vr0 * 1024 + ((vgp ^ (vr0 & 15)) * 8);
  const int voff1 = vr1 * 1024 + ((vgp ^ (vr1 & 15)) * 8);
  const int voff2 = vr2 * 1024 + ((vgp ^ (vr2 & 15)) * 8);
  const int voff3 = vr3 * 1024 + ((vgp ^ (vr3 & 15)) * 8);

  char* pw = (char*)Ps + w * 4096;

  const int b = bh >> 4, h = bh & 15;

#pragma unroll 1
  for (int hp = 0; hp < 2; hp++) {
    const int qi = hp == 0 ? (7 - pp) : pp;
    const int qw = qi * 128 + w * 32;
    const int qmax = qw + 31;

    bf16x8 qf[2][2];
#pragma unroll
    for (int qn = 0; qn < 2; qn++) {
      const unsigned short* qp = Qb + (qw + qn * 16 + lrow) * 64 + lk * 8;
      qf[qn][0] = *(const bf16x8*)qp;
      qf[qn][1] = *(const bf16x8*)(qp + 32);
    }

    f32x4 m[2], lsum[2], yacc[2][4];
#pragma unroll
    for (int qn = 0; qn < 2; qn++) {
      m[qn] = (f32x4){MASKNEG, MASKNEG, MASKNEG, MASKNEG};
      lsum[qn] = (f32x4){0.f, 0.f, 0.f, 0.f};
#pragma unroll
      for (int ef = 0; ef < 4; ef++) yacc[qn][ef] = (f32x4){0.f, 0.f, 0.f, 0.f};
    }

    const int nt = qi + 1;

    {
      char* kb = (char*)Ks + w * 4096;
      char* vb2 = (char*)Vs + w * 4096;
      gload16(kgsrc + 0,    kb);
      gload16(kgsrc + 512,  kb + 1024);
      gload16(kgsrc + 1024, kb + 2048);
      gload16(kgsrc + 1536, kb + 3072);
      gload16(Vb + voff0, vb2);
      gload16(Vb + voff1, vb2 + 1024);
      gload16(Vb + voff2, vb2 + 2048);
      gload16(Vb + voff3, vb2 + 3072);
    }
    __syncthreads();

#pragma unroll 1
    for (int t = 0; t < nt; t++) {
      const int z0 = t * 128;
      const int cur = t & 1;
      if (t < nt - 1) {
        const int zn = (t + 1) * 128;
        char* kb = (char*)Ks + (cur ^ 1) * 16384 + w * 4096;
        char* vb2 = (char*)Vs + (cur ^ 1) * 16384 + w * 4096;
        const unsigned short* kgt = kgsrc + zn * 64;
        gload16(kgt + 0,    kb);
        gload16(kgt + 512,  kb + 1024);
        gload16(kgt + 1024, kb + 2048);
        gload16(kgt + 1536, kb + 3072);
        gload16(Vb + voff0 + zn, vb2);
        gload16(Vb + voff1 + zn, vb2 + 1024);
        gload16(Vb + voff2 + zn, vb2 + 2048);
        gload16(Vb + voff3 + zn, vb2 + 3072);
      }

      if (z0 <= qmax) {
        const char* kbase = (const char*)Ks + cur * 16384;
        const char* vbase = (const char*)Vs + cur * 16384;

        f32x4 s[2][8];
#pragma unroll
        for (int qn = 0; qn < 2; qn++)
#pragma unroll
          for (int zf = 0; zf < 8; zf++) s[qn][zf] = (f32x4){0.f, 0.f, 0.f, 0.f};
#pragma unroll
        for (int zf = 0; zf < 8; zf++) {
          int zr = zf * 16 + lrow;
#pragma unroll
          for (int kf = 0; kf < 2; kf++) {
            bf16x8 kfr = *(const bf16x8*)(kbase + zr * 128 + (((kf * 4 + lk) ^ (zr & 7)) << 4));
            s[0][zf] = mfma16(qf[0][kf], kfr, s[0][zf]);
            s[1][zf] = mfma16(qf[1][kf], kfr, s[1][zf]);
          }
        }

        if (z0 + 127 > qw) {
#pragma unroll
          for (int qn = 0; qn < 2; qn++) {
            int qbase = qw + qn * 16 + 4 * lk;
#pragma unroll
            for (int zf = 0; zf < 8; zf++) {
              int zg = z0 + zf * 16 + lrow;
#pragma unroll
              for (int j = 0; j < 4; j++)
                if (zg > qbase + j) s[qn][zf][j] = MASKNEG;
            }
          }
        }

#pragma unroll
        for (int qn = 0; qn < 2; qn++) {
          f32x4 rm4 = s[qn][0];
#pragma unroll
          for (int zf = 1; zf < 8; zf++)
#pragma unroll
            for (int j = 0; j < 4; j++) rm4[j] = fmaxf(rm4[j], s[qn][zf][j]);
#pragma unroll
          for (int j = 0; j < 4; j++) {
            float r = rm4[j];
            r = fmaxf(r, __shfl_xor(r, 1));
            r = fmaxf(r, __shfl_xor(r, 2));
            r = fmaxf(r, __shfl_xor(r, 4));
            r = fmaxf(r, __shfl_xor(r, 8));
            rm4[j] = r;
          }
          int trig = (rm4[0] > m[qn][0] + 8.f) | (rm4[1] > m[qn][1] + 8.f) |
                     (rm4[2] > m[qn][2] + 8.f) | (rm4[3] > m[qn][3] + 8.f);
          if (__any(trig)) {
#pragma unroll
            for (int j = 0; j < 4; j++) {
              float mn = fmaxf(m[qn][j], rm4[j]);
              float a = __builtin_amdgcn_exp2f(m[qn][j] - mn);
              m[qn][j] = mn;
              lsum[qn][j] *= a;
#pragma unroll
              for (int ef = 0; ef < 4; ef++) yacc[qn][ef][j] *= a;
            }
          }
#pragma unroll
          for (int zf = 0; zf < 8; zf++)
#pragma unroll
            for (int j = 0; j < 4; j++)
              s[qn][zf][j] = __builtin_amdgcn_exp2f(s[qn][zf][j] - m[qn][j]);
        }

#pragma unroll
        for (int hf = 0; hf < 2; hf++) {
          if (z0 + hf * 64 <= qmax) {
#pragma unroll
            for (int qn = 0; qn < 2; qn++) {
#pragma unroll
              for (int zf2 = 0; zf2 < 4; zf2++) {
                int zfg = hf * 4 + zf2;
                int zc = zf2 * 16 + lrow;
                int zp = zc >> 3;
#pragma unroll
                for (int j = 0; j < 4; j++) {
                  int q = 4 * lk + j;
                  *(unsigned short*)(pw + (qn * 16 + q) * 128 + ((zp ^ (q & 7)) << 4) + (zc & 7) * 2)
                      = f2bf(s[qn][zfg][j]);
                }
              }
            }

            asm volatile("s_waitcnt lgkmcnt(0)" ::: "memory");
            __builtin_amdgcn_sched_barrier(0);

            bf16x8 pf[2][2];
#pragma unroll
            for (int qn = 0; qn < 2; qn++)
#pragma unroll
              for (int kf = 0; kf < 2; kf++)
                pf[qn][kf] = *(const bf16x8*)(pw + (qn * 16 + lrow) * 128 + (((kf * 4 + lk) ^ (lrow & 7)) << 4));

#pragma unroll
            for (int qn = 0; qn < 2; qn++)
#pragma unroll
              for (int kf = 0; kf < 2; kf++)
                lsum[qn] = mfma16(pf[qn][kf], ones, lsum[qn]);

#pragma unroll
            for (int ef = 0; ef < 4; ef++) {
              int er = ef * 16 + lrow;
#pragma unroll
              for (int kf = 0; kf < 2; kf++) {
                int g = hf * 8 + kf * 4 + lk;
                bf16x8 vf = *(const bf16x8*)(vbase + er * 256 + ((g ^ (er & 15)) << 4));
                yacc[0][ef] = mfma16(pf[0][kf], vf, yacc[0][ef]);
                yacc[1][ef] = mfma16(pf[1][kf], vf, yacc[1][ef]);
              }
            }
          }
        }
      }

      __syncthreads();
    }

#pragma unroll
    for (int qn = 0; qn < 2; qn++) {
      f32x4 rinv;
#pragma unroll
      for (int j = 0; j < 4; j++) rinv[j] = 1.0f / lsum[qn][j];
#pragma unroll
      for (int ef = 0; ef < 4; ef++) {
        int col = h * 64 + ef * 16 + lrow;
#pragma unroll
        for (int j = 0; j < 4; j++) {
          int x = qw + qn * 16 + lk * 4 + j;
          Y[(b * 1024 + x) * 1024 + col] = f2bf(yacc[qn][ef][j] * rinv[j]);
        }
      }
    }
  }
}

// ---------------- launch ----------------
extern "C" void kernel_launch(void* const* d_in, const int* in_sizes, int n_in,
                              void* d_out, int out_size, void* d_ws, size_t ws_size,
                              hipStream_t stream) {
  const float* x  = (const float*)d_in[0];
  const float* z  = (const float*)d_in[1];
  const float* Wq = (const float*)d_in[2];
  const float* bq = (const float*)d_in[3];
  const float* Wk = (const float*)d_in[4];
  const float* bk = (const float*)d_in[5];
  const float* Wv = (const float*)d_in[6];
  const float* bv = (const float*)d_in[7];
  const float* Wp = (const float*)d_in[8];
  const float* bp = (const float*)d_in[9];
  (void)in_sizes; (void)n_in; (void)out_size; (void)ws_size;

  char* ws = (char*)d_ws;
  unsigned short* Xb  = (unsigned short*)(ws + 0);
  unsigned short* Zb  = (unsigned short*)(ws + 16777216);
  unsigned short* Wqt = (unsigned short*)(ws + 33554432);  // Wqt/Wkt/Wvt contiguous = Wqkv
  unsigned short* Wkt = (unsigned short*)(ws + 35651584);
  unsigned short* Wvt = (unsigned short*)(ws + 37748736);
  unsigned short* Wpt = (unsigned short*)(ws + 39845888);
  unsigned short* Qp  = (unsigned short*)(ws + 41943040);
  unsigned short* Kp  = (unsigned short*)(ws + 58720256);
  unsigned short* Vtp = (unsigned short*)(ws + 75497472);

  k_cvt2<<<dim3(2048), dim3(256), 0, stream>>>(x, z, Xb);
  k_pack<<<dim3(16, 16, 4), dim3(256), 0, stream>>>(Wq, Wk, Wv, Wp, Wqt, Wkt, Wvt, Wpt);

  k_gemm_qkv<<<dim3(64, 24), dim3(256), 0, stream>>>(Xb, Zb, Wqt, bq, bk, bv, Qp, Kp, Vtp);

  k_attn<<<dim3(4, 128), dim3(256), 0, stream>>>(Qp, Kp, Vtp, Xb /*Y*/);

  k_gemm<<<dim3(64, 8), dim3(256), 0, stream>>>(Xb, Wpt, bp, d_out, 3, 1.0f);
}

// Round 14
// 151.799 us; speedup vs baseline: 1.2014x; 1.0328x over previous
//
#include <hip/hip_runtime.h>
#include <stdint.h>

// Pipeline: cvt x,z -> bf16; pack weights; fused QKV GEMM (r12-validated 256x128 ring,
// counted vmcnt(6), 72KB LDS); flash attention (swapped-operand QK^T, in-lane softmax,
// KVBLK=128, defer-max, vectorized P-writes); output GEMM -> f32.
// v_cvt_pk_bf16_f32 inline asm is BANNED (NaN culprit: r11 vs r12 isolation).
// B=8 TX=TZ=1024 DX=DZ=1024 DATT=DMID=64 H=16 DOUT=1024.

typedef float    f32x4  __attribute__((ext_vector_type(4)));
typedef __bf16   bf16x8 __attribute__((ext_vector_type(8)));
typedef unsigned short u16x4 __attribute__((ext_vector_type(4)));
typedef unsigned short u16x8 __attribute__((ext_vector_type(8)));

#define MASKNEG (-3.0e38f)
#define QSCALE_F (0.125f * 1.4426950408889634f)

__device__ __forceinline__ unsigned short f2bf(float f) {
  unsigned int u = __float_as_uint(f);
  u += 0x7fffu + ((u >> 16) & 1u);   // RNE
  return (unsigned short)(u >> 16);
}

__device__ __forceinline__ void gload16(const void* g, void* s) {
  const __attribute__((address_space(1))) unsigned int* gp =
      (const __attribute__((address_space(1))) unsigned int*)(uintptr_t)g;
  __attribute__((address_space(3))) unsigned int* lp =
      (__attribute__((address_space(3))) unsigned int*)(unsigned int)(uintptr_t)s;
  __builtin_amdgcn_global_load_lds(gp, lp, 16, 0, 0);
}

__device__ __forceinline__ f32x4 mfma16(bf16x8 a, bf16x8 b, f32x4 c) {
  return __builtin_amdgcn_mfma_f32_16x16x32_bf16(a, b, c, 0, 0, 0);
}

// ---------------- prep kernels (r12 verbatim) ----------------

__global__ __launch_bounds__(256) void k_cvt2(const float* __restrict__ x,
                                              const float* __restrict__ z,
                                              unsigned short* __restrict__ out) {
  int i = blockIdx.x * 256 + threadIdx.x;
  const int stride = gridDim.x * 256;
  for (; i < 2097152; i += stride) {
    const float* in = (i < 1048576) ? (x + (size_t)i * 8) : (z + (size_t)(i - 1048576) * 8);
    const f32x4* p = (const f32x4*)in;
    f32x4 a = p[0], b = p[1];
    u16x8 o;
    o[0] = f2bf(a[0]); o[1] = f2bf(a[1]); o[2] = f2bf(a[2]); o[3] = f2bf(a[3]);
    o[4] = f2bf(b[0]); o[5] = f2bf(b[1]); o[6] = f2bf(b[2]); o[7] = f2bf(b[3]);
    *(u16x8*)(out + (size_t)i * 8) = o;
  }
}

__global__ __launch_bounds__(256) void k_pack(const float* __restrict__ Wq,
                                              const float* __restrict__ Wk,
                                              const float* __restrict__ Wv,
                                              const float* __restrict__ Wp,
                                              unsigned short* __restrict__ Oq,
                                              unsigned short* __restrict__ Ok,
                                              unsigned short* __restrict__ Ov,
                                              unsigned short* __restrict__ Op) {
  __shared__ float tile[64][65];
  const int t = threadIdx.x;
  const int zid = blockIdx.z;
  if (zid < 3) {
    const float* W = zid == 0 ? Wq : (zid == 1 ? Wk : Wv);
    unsigned short* O = zid == 0 ? Oq : (zid == 1 ? Ok : Ov);
    const int h = blockIdx.x, d0 = blockIdx.y * 64;
    const int ee = t & 63, r0 = t >> 6;
#pragma unroll
    for (int dd = r0; dd < 64; dd += 4)
      tile[dd][ee] = W[(h * 1024 + d0 + dd) * 64 + ee];
    __syncthreads();
    const int d = t & 63, e0 = t >> 6;
#pragma unroll
    for (int e = e0; e < 64; e += 4)
      O[(h * 64 + e) * 1024 + d0 + d] = f2bf(tile[d][e]);
  } else {
    const int k0 = blockIdx.x * 64, n0 = blockIdx.y * 64;
    const int nn = t & 63, r0 = t >> 6;
#pragma unroll
    for (int kk = r0; kk < 64; kk += 4)
      tile[kk][nn] = Wp[(k0 + kk) * 1024 + n0 + nn];
    __syncthreads();
    const int kk = t & 63, e0 = t >> 6;
#pragma unroll
    for (int n2 = e0; n2 < 64; n2 += 4)
      Op[(n0 + n2) * 1024 + k0 + kk] = f2bf(tile[kk][n2]);
  }
}

// ---------------- GEMM body: C[256x128 tile] = A * Bt^T + bias (r12 verbatim) ----------------
// 4 waves, per-wave 128x64 output (acc[8][4]). 3-slot ring, counted vmcnt(6).
// As: 3 slots x 16384 B (256 rows x 64 B). Bs: 3 x 8192 B. 72 KB -> 2 blocks/CU.
__device__ __forceinline__ void gemm_body(const unsigned short* __restrict__ A,
                                          const unsigned short* __restrict__ Bt,
                                          const float* __restrict__ bias,
                                          void* __restrict__ outp,
                                          int mode, float oscale,
                                          int brow, int bcol,
                                          unsigned short* As, unsigned short* Bs) {
  const int tid = threadIdx.x;
  const int l = tid & 63, w = tid >> 6;
  const int lrow = l & 15, lk = l >> 4;
  const int wr = (w >> 1) * 128, wc = (w & 1) * 64;

  const int arow = tid >> 2;
  const int asrc = ((tid & 3) ^ ((arow >> 1) & 3)) * 8;
  const unsigned short* ag0 = A + (size_t)(brow + arow) * 1024 + asrc;
  const unsigned short* bg0 = Bt + (size_t)(bcol + arow) * 1024 + asrc;

  int aoff[8], boff[4];
#pragma unroll
  for (int m = 0; m < 8; m++) {
    int row = wr + m * 16 + lrow;
    aoff[m] = row * 64 + ((lk ^ ((row >> 1) & 3)) << 4);
  }
#pragma unroll
  for (int n = 0; n < 4; n++) {
    int col = wc + n * 16 + lrow;
    boff[n] = col * 64 + ((lk ^ ((col >> 1) & 3)) << 4);
  }

  f32x4 acc[8][4];
#pragma unroll
  for (int n = 0; n < 4; n++) {
    float bv = bias[bcol + wc + n * 16 + lrow];
#pragma unroll
    for (int m = 0; m < 8; m++) acc[m][n] = (f32x4){bv, bv, bv, bv};
  }

#define STAGE_G(kt, slot)                                                  \
  {                                                                        \
    char* asb = (char*)As + (slot) * 16384 + w * 1024;                     \
    char* bsb = (char*)Bs + (slot) * 8192 + w * 1024;                      \
    gload16(ag0 + (kt) * 32,          asb);                                \
    gload16(ag0 + (kt) * 32 + 65536,  asb + 4096);                         \
    gload16(ag0 + (kt) * 32 + 131072, asb + 8192);                         \
    gload16(ag0 + (kt) * 32 + 196608, asb + 12288);                        \
    gload16(bg0 + (kt) * 32,          bsb);                                \
    gload16(bg0 + (kt) * 32 + 65536,  bsb + 4096);                         \
  }

  STAGE_G(0, 0)
  STAGE_G(1, 1)
  asm volatile("s_waitcnt vmcnt(6)" ::: "memory");
  __builtin_amdgcn_s_barrier();
  __builtin_amdgcn_sched_barrier(0);

  int s0 = 0, s2 = 2;
#pragma unroll 1
  for (int kt = 0; kt < 32; kt++) {
    if (kt < 30) STAGE_G(kt + 2, s2)
    const char* ab = (const char*)As + s0 * 16384;
    const char* bb = (const char*)Bs + s0 * 8192;
    bf16x8 bfr[4];
#pragma unroll
    for (int n = 0; n < 4; n++) bfr[n] = *(const bf16x8*)(bb + boff[n]);
#pragma unroll
    for (int m = 0; m < 8; m++) {
      bf16x8 af = *(const bf16x8*)(ab + aoff[m]);
#pragma unroll
      for (int n = 0; n < 4; n++)
        acc[m][n] = mfma16(af, bfr[n], acc[m][n]);
    }
    if (kt < 31) {
      if (kt < 30) {
        asm volatile("s_waitcnt vmcnt(6)" ::: "memory");
      } else {
        asm volatile("s_waitcnt vmcnt(0)" ::: "memory");
      }
      __builtin_amdgcn_s_barrier();
      __builtin_amdgcn_sched_barrier(0);
    }
    s0 = (s0 == 2) ? 0 : s0 + 1;
    s2 = (s2 == 2) ? 0 : s2 + 1;
  }
#undef STAGE_G

  if (mode == 0) {
    unsigned short* C = (unsigned short*)outp;
#pragma unroll
    for (int m = 0; m < 8; m++) {
      int r = brow + wr + m * 16 + 4 * lk;
#pragma unroll
      for (int n = 0; n < 4; n++) {
        int c = bcol + wc + n * 16 + lrow;
        unsigned short* p = C + ((r >> 10) * 16 + (c >> 6)) * 65536 + (r & 1023) * 64 + (c & 63);
#pragma unroll
        for (int j = 0; j < 4; j++) p[j * 64] = f2bf(acc[m][n][j] * oscale);
      }
    }
  } else if (mode == 2) {
    unsigned short* C = (unsigned short*)outp;
#pragma unroll
    for (int m = 0; m < 8; m++) {
      int r = brow + wr + m * 16 + 4 * lk;
#pragma unroll
      for (int n = 0; n < 4; n++) {
        int c = bcol + wc + n * 16 + lrow;
        u16x4 o;
#pragma unroll
        for (int j = 0; j < 4; j++) o[j] = f2bf(acc[m][n][j]);
        *(u16x4*)(C + ((r >> 10) * 16 + (c >> 6)) * 65536 + (c & 63) * 1024 + (r & 1023)) = o;
      }
    }
  } else {
    float* C = (float*)outp;
#pragma unroll
    for (int m = 0; m < 8; m++) {
      int r = brow + wr + m * 16 + 4 * lk;
#pragma unroll
      for (int n = 0; n < 4; n++) {
        int c = bcol + wc + n * 16 + lrow;
#pragma unroll
        for (int j = 0; j < 4; j++) C[(r + j) * 1024 + c] = acc[m][n][j];
      }
    }
  }
}

__global__ __launch_bounds__(256, 2) void k_gemm_qkv(const unsigned short* __restrict__ Xb,
                                                     const unsigned short* __restrict__ Zb,
                                                     const unsigned short* __restrict__ Wqkv,
                                                     const float* __restrict__ bq,
                                                     const float* __restrict__ bk,
                                                     const float* __restrict__ bv,
                                                     unsigned short* __restrict__ Qp,
                                                     unsigned short* __restrict__ Kp,
                                                     unsigned short* __restrict__ Vtp) {
  __shared__ unsigned short As[24576];
  __shared__ unsigned short Bs[12288];
  const int brow = blockIdx.x * 256;
  const int cg = blockIdx.y;
  const int seg = cg >> 3;
  const int bcol = (cg & 7) * 128;
  const unsigned short* A = (seg == 0) ? Xb : Zb;
  const unsigned short* Bt = Wqkv + (size_t)seg * 1048576;
  const float* bias = (seg == 0) ? bq : (seg == 1 ? bk : bv);
  void* outp = (seg == 0) ? (void*)Qp : (seg == 1 ? (void*)Kp : (void*)Vtp);
  const int mode = (seg == 2) ? 2 : 0;
  const float oscale = (seg == 0) ? QSCALE_F : 1.0f;
  gemm_body(A, Bt, bias, outp, mode, oscale, brow, bcol, As, Bs);
}

__global__ __launch_bounds__(256, 2) void k_gemm(const unsigned short* __restrict__ A,
                                                 const unsigned short* __restrict__ Bt,
                                                 const float* __restrict__ bias,
                                                 void* __restrict__ outp,
                                                 int mode, float oscale) {
  __shared__ unsigned short As[24576];
  __shared__ unsigned short Bs[12288];
  gemm_body(A, Bt, bias, outp, mode, oscale, blockIdx.x * 256, blockIdx.y * 128, As, Bs);
}

// ---------------- flash attention: swapped QK^T, in-lane softmax, KVBLK=128 ----------------
// S^T = mfma(Kfrag, Qfrag): lane holds S[z = z0+zf*16+4*lk+j][q = qw+qn*16+lrow] —
// a full 32-z P-row slice in-lane per q. Row max: in-lane fmax + 2 shfls (over lk).
// Rescale broadcast (4 shfls) only on defer-max trigger. P written transposed to LDS
// as P[q][z] rows via vectorized u16x4 (lane owns 4 consecutive z of one row); P-read,
// PV, lsum-via-ones-MFMA, epilogue identical to r12 (validated).
__global__ __launch_bounds__(256, 2) void k_attn(const unsigned short* __restrict__ Qh,
                                                 const unsigned short* __restrict__ Kh,
                                                 const unsigned short* __restrict__ Vth,
                                                 unsigned short* __restrict__ Y) {
  __shared__ unsigned short Ks[16384];  // 2 x (128 z x 64 d) swizzled, 32 KB
  __shared__ unsigned short Vs[16384];  // 2 x (64 e x 128 z) swizzled, 32 KB
  __shared__ unsigned short Ps[8192];   // 4 waves x (32 q x 64 z) swizzled, 16 KB

  const int tid = threadIdx.x, l = tid & 63, w = tid >> 6;
  const int lrow = l & 15, lk = l >> 4;
  const int bh = blockIdx.y;
  const int pp = blockIdx.x;

  const unsigned short* Qb = Qh + bh * 65536;
  const unsigned short* Kb = Kh + bh * 65536;
  const unsigned short* Vb = Vth + bh * 65536;

  bf16x8 ones;
#pragma unroll
  for (int j = 0; j < 8; j++) ones[j] = (__bf16)1.0f;

  const int krl = l >> 3;
  const int kgp = l & 7;
  const unsigned short* kgsrc = Kb + (w * 32 + krl) * 64 + ((kgp ^ krl) * 8);
  const int vrl = l >> 4;
  const int vgp = l & 15;
  const int vr0 = w * 16 + 0 * 4 + vrl;
  const int vr1 = w * 16 + 1 * 4 + vrl;
  const int vr2 = w * 16 + 2 * 4 + vrl;
  const int vr3 = w * 16 + 3 * 4 + vrl;
  const int voff0 = vr0 * 1024 + ((vgp ^ (vr0 & 15)) * 8);
  const int voff1 = vr1 * 1024 + ((vgp ^ (vr1 & 15)) * 8);
  const int voff2 = vr2 * 1024 + ((vgp ^ (vr2 & 15)) * 8);
  const int voff3 = vr3 * 1024 + ((vgp ^ (vr3 & 15)) * 8);

  char* pw = (char*)Ps + w * 4096;

  const int b = bh >> 4, h = bh & 15;

#pragma unroll 1
  for (int hp = 0; hp < 2; hp++) {
    const int qi = hp == 0 ? (7 - pp) : pp;
    const int qw = qi * 128 + w * 32;
    const int qmax = qw + 31;

    bf16x8 qf[2][2];
#pragma unroll
    for (int qn = 0; qn < 2; qn++) {
      const unsigned short* qp = Qb + (qw + qn * 16 + lrow) * 64 + lk * 8;
      qf[qn][0] = *(const bf16x8*)qp;
      qf[qn][1] = *(const bf16x8*)(qp + 32);
    }

    float mm[2];
    f32x4 lsum[2], yacc[2][4];
#pragma unroll
    for (int qn = 0; qn < 2; qn++) {
      mm[qn] = MASKNEG;
      lsum[qn] = (f32x4){0.f, 0.f, 0.f, 0.f};
#pragma unroll
      for (int ef = 0; ef < 4; ef++) yacc[qn][ef] = (f32x4){0.f, 0.f, 0.f, 0.f};
    }

    const int nt = qi + 1;

    {
      char* kb = (char*)Ks + w * 4096;
      char* vb2 = (char*)Vs + w * 4096;
      gload16(kgsrc + 0,    kb);
      gload16(kgsrc + 512,  kb + 1024);
      gload16(kgsrc + 1024, kb + 2048);
      gload16(kgsrc + 1536, kb + 3072);
      gload16(Vb + voff0, vb2);
      gload16(Vb + voff1, vb2 + 1024);
      gload16(Vb + voff2, vb2 + 2048);
      gload16(Vb + voff3, vb2 + 3072);
    }
    __syncthreads();

#pragma unroll 1
    for (int t = 0; t < nt; t++) {
      const int z0 = t * 128;
      const int cur = t & 1;
      if (t < nt - 1) {
        const int zn = (t + 1) * 128;
        char* kb = (char*)Ks + (cur ^ 1) * 16384 + w * 4096;
        char* vb2 = (char*)Vs + (cur ^ 1) * 16384 + w * 4096;
        const unsigned short* kgt = kgsrc + zn * 64;
        gload16(kgt + 0,    kb);
        gload16(kgt + 512,  kb + 1024);
        gload16(kgt + 1024, kb + 2048);
        gload16(kgt + 1536, kb + 3072);
        gload16(Vb + voff0 + zn, vb2);
        gload16(Vb + voff1 + zn, vb2 + 1024);
        gload16(Vb + voff2 + zn, vb2 + 2048);
        gload16(Vb + voff3 + zn, vb2 + 3072);
      }

      if (z0 <= qmax) {
        const char* kbase = (const char*)Ks + cur * 16384;
        const char* vbase = (const char*)Vs + cur * 16384;

        // S^T: lane holds S[z = z0 + zf*16 + 4*lk + j][q = qw + qn*16 + lrow]
        f32x4 s[2][8];
#pragma unroll
        for (int qn = 0; qn < 2; qn++)
#pragma unroll
          for (int zf = 0; zf < 8; zf++) s[qn][zf] = (f32x4){0.f, 0.f, 0.f, 0.f};
#pragma unroll
        for (int zf = 0; zf < 8; zf++) {
          int zr = zf * 16 + lrow;
#pragma unroll
          for (int kf = 0; kf < 2; kf++) {
            bf16x8 kfr = *(const bf16x8*)(kbase + zr * 128 + (((kf * 4 + lk) ^ (zr & 7)) << 4));
            s[0][zf] = mfma16(kfr, qf[0][kf], s[0][zf]);
            s[1][zf] = mfma16(kfr, qf[1][kf], s[1][zf]);
          }
        }

        if (z0 + 127 > qw) {   // diagonal overlap: mask z > q
#pragma unroll
          for (int qn = 0; qn < 2; qn++) {
            int qg = qw + qn * 16 + lrow;
#pragma unroll
            for (int zf = 0; zf < 8; zf++) {
              int zb = z0 + zf * 16 + 4 * lk;
#pragma unroll
              for (int j = 0; j < 4; j++)
                if (zb + j > qg) s[qn][zf][j] = MASKNEG;
            }
          }
        }

        // in-lane softmax: 31 fmax + 2 shfls; defer-max THR=8 (log2 domain)
#pragma unroll
        for (int qn = 0; qn < 2; qn++) {
          f32x4 r4 = s[qn][0];
#pragma unroll
          for (int zf = 1; zf < 8; zf++)
#pragma unroll
            for (int j = 0; j < 4; j++) r4[j] = fmaxf(r4[j], s[qn][zf][j]);
          float rm = fmaxf(fmaxf(r4[0], r4[1]), fmaxf(r4[2], r4[3]));
          rm = fmaxf(rm, __shfl_xor(rm, 16));
          rm = fmaxf(rm, __shfl_xor(rm, 32));

          if (__any(rm > mm[qn] + 8.f)) {
            float mn = fmaxf(mm[qn], rm);
            float a = __builtin_amdgcn_exp2f(mm[qn] - mn);  // <= 0 arg
            mm[qn] = mn;
            f32x4 av;
#pragma unroll
            for (int j = 0; j < 4; j++)
              av[j] = __shfl(a, (l & 48) | (lk * 4 + j));
            lsum[qn] *= av;
#pragma unroll
            for (int ef = 0; ef < 4; ef++) yacc[qn][ef] *= av;
          }
          float mk = mm[qn];
#pragma unroll
          for (int zf = 0; zf < 8; zf++)
#pragma unroll
            for (int j = 0; j < 4; j++)
              s[qn][zf][j] = __builtin_amdgcn_exp2f(s[qn][zf][j] - mk);  // <= 2^8
        }

        // PV in two 64-z halves
#pragma unroll
        for (int hf = 0; hf < 2; hf++) {
          if (z0 + hf * 64 <= qmax) {
            // P^T -> P[q][z] rows in LDS: lane writes 4 consecutive z of row q (u16x4)
#pragma unroll
            for (int qn = 0; qn < 2; qn++) {
              int q = qn * 16 + lrow;
              char* rowp = pw + q * 128;
#pragma unroll
              for (int zf2 = 0; zf2 < 4; zf2++) {
                int zfg = hf * 4 + zf2;
                u16x4 o;
#pragma unroll
                for (int j = 0; j < 4; j++) o[j] = f2bf(s[qn][zfg][j]);
                int g = zf2 * 2 + (lk >> 1);
                *(u16x4*)(rowp + ((g ^ (q & 7)) << 4) + (lk & 1) * 8) = o;
              }
            }

            asm volatile("s_waitcnt lgkmcnt(0)" ::: "memory");
            __builtin_amdgcn_sched_barrier(0);

            // P-read / lsum / PV (r12 verbatim)
            bf16x8 pf[2][2];
#pragma unroll
            for (int qn = 0; qn < 2; qn++)
#pragma unroll
              for (int kf = 0; kf < 2; kf++)
                pf[qn][kf] = *(const bf16x8*)(pw + (qn * 16 + lrow) * 128 + (((kf * 4 + lk) ^ (lrow & 7)) << 4));

#pragma unroll
            for (int qn = 0; qn < 2; qn++)
#pragma unroll
              for (int kf = 0; kf < 2; kf++)
                lsum[qn] = mfma16(pf[qn][kf], ones, lsum[qn]);

#pragma unroll
            for (int ef = 0; ef < 4; ef++) {
              int er = ef * 16 + lrow;
#pragma unroll
              for (int kf = 0; kf < 2; kf++) {
                int g = hf * 8 + kf * 4 + lk;
                bf16x8 vf = *(const bf16x8*)(vbase + er * 256 + ((g ^ (er & 15)) << 4));
                yacc[0][ef] = mfma16(pf[0][kf], vf, yacc[0][ef]);
                yacc[1][ef] = mfma16(pf[1][kf], vf, yacc[1][ef]);
              }
            }
          }
        }
      }

      __syncthreads();
    }

    // epilogue (r12 verbatim): q = qw + qn*16 + lk*4 + j, e = ef*16 + lrow
#pragma unroll
    for (int qn = 0; qn < 2; qn++) {
      f32x4 rinv;
#pragma unroll
      for (int j = 0; j < 4; j++) rinv[j] = 1.0f / lsum[qn][j];
#pragma unroll
      for (int ef = 0; ef < 4; ef++) {
        int col = h * 64 + ef * 16 + lrow;
#pragma unroll
        for (int j = 0; j < 4; j++) {
          int x = qw + qn * 16 + lk * 4 + j;
          Y[(b * 1024 + x) * 1024 + col] = f2bf(yacc[qn][ef][j] * rinv[j]);
        }
      }
    }
  }
}

// ---------------- launch ----------------
extern "C" void kernel_launch(void* const* d_in, const int* in_sizes, int n_in,
                              void* d_out, int out_size, void* d_ws, size_t ws_size,
                              hipStream_t stream) {
  const float* x  = (const float*)d_in[0];
  const float* z  = (const float*)d_in[1];
  const float* Wq = (const float*)d_in[2];
  const float* bq = (const float*)d_in[3];
  const float* Wk = (const float*)d_in[4];
  const float* bk = (const float*)d_in[5];
  const float* Wv = (const float*)d_in[6];
  const float* bv = (const float*)d_in[7];
  const float* Wp = (const float*)d_in[8];
  const float* bp = (const float*)d_in[9];
  (void)in_sizes; (void)n_in; (void)out_size; (void)ws_size;

  char* ws = (char*)d_ws;
  unsigned short* Xb  = (unsigned short*)(ws + 0);
  unsigned short* Zb  = (unsigned short*)(ws + 16777216);
  unsigned short* Wqt = (unsigned short*)(ws + 33554432);  // Wqt/Wkt/Wvt contiguous = Wqkv
  unsigned short* Wkt = (unsigned short*)(ws + 35651584);
  unsigned short* Wvt = (unsigned short*)(ws + 37748736);
  unsigned short* Wpt = (unsigned short*)(ws + 39845888);
  unsigned short* Qp  = (unsigned short*)(ws + 41943040);
  unsigned short* Kp  = (unsigned short*)(ws + 58720256);
  unsigned short* Vtp = (unsigned short*)(ws + 75497472);

  k_cvt2<<<dim3(2048), dim3(256), 0, stream>>>(x, z, Xb);
  k_pack<<<dim3(16, 16, 4), dim3(256), 0, stream>>>(Wq, Wk, Wv, Wp, Wqt, Wkt, Wvt, Wpt);

  k_gemm_qkv<<<dim3(32, 24), dim3(256), 0, stream>>>(Xb, Zb, Wqt, bq, bk, bv, Qp, Kp, Vtp);

  k_attn<<<dim3(4, 128), dim3(256), 0, stream>>>(Qp, Kp, Vtp, Xb /*Y*/);

  k_gemm<<<dim3(32, 8), dim3(256), 0, stream>>>(Xb, Wpt, bp, d_out, 3, 1.0f);
}